// Round 2
// baseline (1311.849 us; speedup 1.0000x reference)
//
#include <hip/hip_runtime.h>

#define GRID 48
#define NB 64
#define NNODES (NB * GRID * GRID)   // 147456

// ---------------------------------------------------------------------------
__global__ void zero_buf(float* __restrict__ p, int n) {
    int i = blockIdx.x * blockDim.x + threadIdx.x;
    if (i < n) p[i] = 0.f;
}

// ---------------------------------------------------------------------------
// Tiled fp32 GEMM: Y[n,M] = A[n,K] @ W[K,M] (+ bias)
// ---------------------------------------------------------------------------
__global__ void gemm_bias(const float* __restrict__ A, const float* __restrict__ W,
                          const float* __restrict__ bias, float* __restrict__ Y,
                          int n, int K, int M) {
    __shared__ float As[16][16];
    __shared__ float Ws[16][17];
    int row = blockIdx.y * 16 + threadIdx.y;
    int col = blockIdx.x * 16 + threadIdx.x;
    float acc = 0.f;
    for (int k0 = 0; k0 < K; k0 += 16) {
        int ka = k0 + threadIdx.x;
        As[threadIdx.y][threadIdx.x] =
            (row < n && ka < K) ? A[(size_t)row * K + ka] : 0.f;
        int kw = k0 + threadIdx.y;
        Ws[threadIdx.y][threadIdx.x] =
            (kw < K && col < M) ? W[(size_t)kw * M + col] : 0.f;
        __syncthreads();
#pragma unroll
        for (int kk = 0; kk < 16; ++kk)
            acc += As[threadIdx.y][kk] * Ws[kk][threadIdx.x];
        __syncthreads();
    }
    if (row < n && col < M)
        Y[(size_t)row * M + col] = acc + (bias ? bias[col] : 0.f);
}

// ---------------------------------------------------------------------------
// Per-column sum & sum-of-squares over (N, M) row-major matrix.
// ---------------------------------------------------------------------------
__global__ void colstats(const float* __restrict__ Y, long long total, int M,
                         float* __restrict__ sum, float* __restrict__ ss) {
    extern __shared__ float sm[];  // 2*M floats
    float* s1 = sm;
    float* s2 = sm + M;
    for (int f = threadIdx.x; f < 2 * M; f += blockDim.x) sm[f] = 0.f;
    __syncthreads();
    long long stride = (long long)gridDim.x * blockDim.x;
    for (long long i = (long long)blockIdx.x * blockDim.x + threadIdx.x; i < total; i += stride) {
        float v = Y[i];
        int f = (int)(i % M);
        atomicAdd(&s1[f], v);
        atomicAdd(&s2[f], v * v);
    }
    __syncthreads();
    for (int f = threadIdx.x; f < M; f += blockDim.x) {
        atomicAdd(&sum[f], s1[f]);
        atomicAdd(&ss[f], s2[f]);
    }
}

// ---------------------------------------------------------------------------
// Fold BN stats into scale/shift: a = gamma*rsqrt(var+eps), b = beta - mean*a
// ---------------------------------------------------------------------------
__global__ void bn_finalize(int M, const float* __restrict__ sum, const float* __restrict__ ss,
                            const float* __restrict__ gamma, const float* __restrict__ beta,
                            float* __restrict__ a, float* __restrict__ b, float invN) {
    int f = blockIdx.x * blockDim.x + threadIdx.x;
    if (f < M) {
        float m = sum[f] * invN;
        float v = ss[f] * invN - m * m;
        float sc = gamma[f] * rsqrtf(v + 1e-5f);
        a[f] = sc;
        b[f] = beta[f] - m * sc;
    }
}

__global__ void scaleshift(float* __restrict__ Y, long long total, int M,
                           const float* __restrict__ a, const float* __restrict__ b) {
    long long stride = (long long)gridDim.x * blockDim.x;
    for (long long i = (long long)blockIdx.x * blockDim.x + threadIdx.x; i < total; i += stride) {
        int f = (int)(i % M);
        Y[i] = Y[i] * a[f] + b[f];
    }
}

// ---------------------------------------------------------------------------
// GMM stencil: rc[i,o] (holds r = h1@w2+b2) += (1/deg) * sum over 3x3 valid
// neighbors j, sum over kernels k of gauss[d][k] * t[j, k*44+o].
// gauss depends only on the offset (dx,dy): ea = (dx,dy)*0.5 + 0.5.
// ---------------------------------------------------------------------------
__global__ void gmm_stencil(const float* __restrict__ t, float* __restrict__ rc,
                            const float* __restrict__ mu, const float* __restrict__ sigma) {
    __shared__ float gs[9][3];
    if (threadIdx.x < 27) {
        int d = threadIdx.x / 3, k = threadIdx.x % 3;
        int dx = d / 3 - 1, dy = d % 3 - 1;
        float ex = 0.5f * (float)dx + 0.5f;
        float ey = 0.5f * (float)dy + 0.5f;
        float mx = mu[k * 2 + 0], my = mu[k * 2 + 1];
        float sx = sigma[k * 2 + 0], sy = sigma[k * 2 + 1];
        float q = -0.5f * ((ex - mx) * (ex - mx) / (1e-15f + sx * sx) +
                           (ey - my) * (ey - my) / (1e-15f + sy * sy));
        gs[d][k] = expf(q);
    }
    __syncthreads();
    long long idx = (long long)blockIdx.x * blockDim.x + threadIdx.x;
    if (idx >= (long long)NNODES * 44) return;
    int node = (int)(idx / 44);
    int o = (int)(idx % 44);
    int rem = node % (GRID * GRID);
    int ix = rem / GRID, iy = rem % GRID;
    float acc = 0.f;
    int cnt = 0;
#pragma unroll
    for (int dx = -1; dx <= 1; ++dx) {
        int jx = ix + dx;
        if (jx < 0 || jx >= GRID) continue;
#pragma unroll
        for (int dy = -1; dy <= 1; ++dy) {
            int jy = iy + dy;
            if (jy < 0 || jy >= GRID) continue;
            int j = node + dx * GRID + dy;
            int d = (dx + 1) * 3 + (dy + 1);
            const float* tj = t + (size_t)j * 132 + o;
            acc += gs[d][0] * tj[0] + gs[d][1] * tj[44] + gs[d][2] * tj[88];
            ++cnt;
        }
    }
    rc[idx] = acc / (float)cnt + rc[idx];
}

// ---------------------------------------------------------------------------
extern "C" void kernel_launch(void* const* d_in, const int* in_sizes, int n_in,
                              void* d_out, int out_size, void* d_ws, size_t ws_size,
                              hipStream_t stream) {
    const float* x      = (const float*)d_in[0];   // (N,128)
    // d_in[1] pos, d_in[2] edge_index: unused (grid structure is static)
    const float* w0     = (const float*)d_in[3];   // (128,102)
    const float* b0     = (const float*)d_in[4];
    const float* gamma0 = (const float*)d_in[5];
    const float* beta0  = (const float*)d_in[6];
    const float* w1     = (const float*)d_in[7];   // (102,73)
    const float* b1     = (const float*)d_in[8];
    const float* gamma1 = (const float*)d_in[9];
    const float* beta1  = (const float*)d_in[10];
    const float* w2     = (const float*)d_in[11];  // (73,44)
    const float* g2     = (const float*)d_in[12];  // (73,132)
    const float* mu2    = (const float*)d_in[13];  // (3,2)
    const float* sigma2 = (const float*)d_in[14];  // (3,2)
    const float* b2     = (const float*)d_in[15];
    const float* gamma2 = (const float*)d_in[16];
    const float* beta2  = (const float*)d_in[17];
    const float* w3     = (const float*)d_in[18];  // (44,16)
    const float* b3     = (const float*)d_in[19];
    float* out = (float*)d_out;

    const int N = NNODES;
    const float invN = 1.0f / (float)N;

    // Workspace layout (peak 249 cols * N * 4B ~= 147 MB + 1 KB stats).
    // Guard: if ws_size is too small, bail out rather than corrupt the heap
    // (bench will fail validation loudly instead of killing the container).
    size_t need = ((size_t)N * (132 + 73 + 44) + 1024) * sizeof(float);
    if (ws_size < need) return;

    float* ws = (float*)d_ws;
    float* bufA = ws;                      // N*132 (y0/h0 then t)
    float* bufB = bufA + (size_t)N * 132;  // N*73  (y1/h1)
    float* bufC = bufB + (size_t)N * 73;   // N*44  (r -> y2 -> h2)
    float* stats = bufC + (size_t)N * 44;  // sums/ss: 102+102+73+73+44+44 = 438
    float* sum0 = stats,       *ss0 = sum0 + 102;
    float* sum1 = ss0 + 102,   *ss1 = sum1 + 73;
    float* sum2 = ss1 + 73,    *ss2 = sum2 + 44;
    float* par  = stats + 512;             // a/b per layer
    float* a0 = par,        *sh0 = a0 + 102;
    float* a1 = sh0 + 102,  *sh1 = a1 + 73;
    float* a2 = sh1 + 73,   *sh2 = a2 + 44;

    zero_buf<<<2, 256, 0, stream>>>(stats, 438);

    dim3 tb(16, 16);
    int rowBlocks = (N + 15) / 16;

    // ---- layer 0: y0 = x @ w0 + b0 ; BN ----
    gemm_bias<<<dim3((102 + 15) / 16, rowBlocks), tb, 0, stream>>>(x, w0, b0, bufA, N, 128, 102);
    colstats<<<2048, 256, 2 * 102 * sizeof(float), stream>>>(bufA, (long long)N * 102, 102, sum0, ss0);
    bn_finalize<<<1, 128, 0, stream>>>(102, sum0, ss0, gamma0, beta0, a0, sh0, invN);
    scaleshift<<<4096, 256, 0, stream>>>(bufA, (long long)N * 102, 102, a0, sh0);

    // ---- layer 1: y1 = h0 @ w1 + b1 ; BN ----
    gemm_bias<<<dim3((73 + 15) / 16, rowBlocks), tb, 0, stream>>>(bufA, w1, b1, bufB, N, 102, 73);
    colstats<<<2048, 256, 2 * 73 * sizeof(float), stream>>>(bufB, (long long)N * 73, 73, sum1, ss1);
    bn_finalize<<<1, 128, 0, stream>>>(73, sum1, ss1, gamma1, beta1, a1, sh1, invN);
    scaleshift<<<4096, 256, 0, stream>>>(bufB, (long long)N * 73, 73, a1, sh1);

    // ---- layer 2: t = h1 @ g2 ; r = h1 @ w2 + b2 ; stencil ; BN ----
    gemm_bias<<<dim3((132 + 15) / 16, rowBlocks), tb, 0, stream>>>(bufB, g2, nullptr, bufA, N, 73, 132);
    gemm_bias<<<dim3((44 + 15) / 16, rowBlocks), tb, 0, stream>>>(bufB, w2, b2, bufC, N, 73, 44);
    {
        long long tot = (long long)N * 44;
        int blocks = (int)((tot + 255) / 256);
        gmm_stencil<<<blocks, 256, 0, stream>>>(bufA, bufC, mu2, sigma2);
    }
    colstats<<<2048, 256, 2 * 44 * sizeof(float), stream>>>(bufC, (long long)N * 44, 44, sum2, ss2);
    bn_finalize<<<1, 64, 0, stream>>>(44, sum2, ss2, gamma2, beta2, a2, sh2, invN);
    scaleshift<<<4096, 256, 0, stream>>>(bufC, (long long)N * 44, 44, a2, sh2);

    // ---- output: out = h2 @ w3 + b3 ----
    gemm_bias<<<dim3(1, rowBlocks), tb, 0, stream>>>(bufC, w3, b3, out, N, 44, 16);
}

// Round 3
// 680.803 us; speedup vs baseline: 1.9269x; 1.9269x over previous
//
#include <hip/hip_runtime.h>

#define GRID 48
#define NB 64
#define NNODES (NB * GRID * GRID)   // 147456 = 2304 * 64 (row tiles exact)

__global__ void zero_buf(float* __restrict__ p, int n) {
    int i = blockIdx.x * blockDim.x + threadIdx.x;
    if (i < n) p[i] = 0.f;
}

// ---------------------------------------------------------------------------
// Register-tiled fp32 GEMM: Y[n,M] = op(A)[n,K] @ W[K,M] + bias
//   op(A)[r][k] = APPLY_IN ? A[r][k]*ain[k]+bin[k] : A[r][k]   (fused BN of prev layer)
//   STATS: per-column sum & sum-of-squares of Y atomically accumulated (fused BN stats)
// Block: 256 threads, 64x64 tile, 4x4 outputs/thread, K-tile 16.
// n assumed multiple of 64 (147456 = 2304*64). M/K arbitrary (guarded).
// ---------------------------------------------------------------------------
template<bool APPLY_IN, bool STATS>
__global__ __launch_bounds__(256) void gemm_rt(
    const float* __restrict__ A, const float* __restrict__ W,
    const float* __restrict__ bias,
    const float* __restrict__ ain, const float* __restrict__ bin,
    float* __restrict__ Y, float* __restrict__ sum, float* __restrict__ ss,
    int K, int M)
{
    __shared__ float As[16][68];   // [k][row], +4 pad keeps writes 2-way max
    __shared__ float Ws[16][68];   // [k][col]
    const int tid = threadIdx.x;
    const int r0 = blockIdx.y * 64;
    const int c0 = blockIdx.x * 64;
    const int tx = tid & 15;       // col group: cols c0 + 4*tx .. +3
    const int ty = tid >> 4;       // row group: rows r0 + 4*ty .. +3

    float4 acc[4];
#pragma unroll
    for (int i = 0; i < 4; ++i) acc[i] = make_float4(0.f, 0.f, 0.f, 0.f);

    const int nk = (K + 15) / 16;
    for (int kt = 0; kt < nk; ++kt) {
        const int k0 = kt * 16;
        // ---- stage A tile (64 rows x 16 k), coalesced scalar, transpose to [k][row]
#pragma unroll
        for (int j = 0; j < 4; ++j) {
            int e = tid + 256 * j;         // 0..1023 over 64x16 tile
            int row = e >> 4;              // 0..63
            int kk = e & 15;               // 0..15
            int kg = k0 + kk;
            float v = 0.f;
            if (kg < K) {
                v = A[(size_t)(r0 + row) * K + kg];
                if (APPLY_IN) { int kc = kg; v = v * ain[kc] + bin[kc]; }
            }
            As[kk][row] = v;
        }
        // ---- stage W tile (16 k x 64 cols), coalesced scalar
#pragma unroll
        for (int j = 0; j < 4; ++j) {
            int e = tid + 256 * j;         // over 16x64 tile, k-major
            int kk = e >> 6;               // 0..15
            int c = e & 63;                // 0..63
            float v = 0.f;
            if (k0 + kk < K && c0 + c < M)
                v = W[(size_t)(k0 + kk) * M + c0 + c];
            Ws[kk][c] = v;
        }
        __syncthreads();
        // ---- compute: 16 k-steps x 16 FMA, LDS reads are b128
#pragma unroll
        for (int kk = 0; kk < 16; ++kk) {
            float4 a4 = *(const float4*)&As[kk][ty << 2];
            float4 w4 = *(const float4*)&Ws[kk][tx << 2];
            acc[0].x += a4.x * w4.x; acc[0].y += a4.x * w4.y; acc[0].z += a4.x * w4.z; acc[0].w += a4.x * w4.w;
            acc[1].x += a4.y * w4.x; acc[1].y += a4.y * w4.y; acc[1].z += a4.y * w4.z; acc[1].w += a4.y * w4.w;
            acc[2].x += a4.z * w4.x; acc[2].y += a4.z * w4.y; acc[2].z += a4.z * w4.z; acc[2].w += a4.z * w4.w;
            acc[3].x += a4.w * w4.x; acc[3].y += a4.w * w4.y; acc[3].z += a4.w * w4.z; acc[3].w += a4.w * w4.w;
        }
        __syncthreads();
    }

    // ---- epilogue: bias, store, fused column stats
    float bj[4];
#pragma unroll
    for (int j = 0; j < 4; ++j) {
        int col = c0 + (tx << 2) + j;
        bj[j] = (bias && col < M) ? bias[col] : 0.f;
    }
    float cs[4] = {0.f, 0.f, 0.f, 0.f};
    float cq[4] = {0.f, 0.f, 0.f, 0.f};
#pragma unroll
    for (int i = 0; i < 4; ++i) {
        int row = r0 + (ty << 2) + i;
        float v[4] = {acc[i].x + bj[0], acc[i].y + bj[1], acc[i].z + bj[2], acc[i].w + bj[3]};
#pragma unroll
        for (int j = 0; j < 4; ++j) {
            int col = c0 + (tx << 2) + j;
            if (col < M) Y[(size_t)row * M + col] = v[j];
            if (STATS) { cs[j] += v[j]; cq[j] += v[j] * v[j]; }
        }
    }
    if (STATS) {
        // reduce 16 ty-groups per column; reuse As (sum) / Ws (sumsq)
        *(float4*)&As[ty][tx << 2] = make_float4(cs[0], cs[1], cs[2], cs[3]);
        *(float4*)&Ws[ty][tx << 2] = make_float4(cq[0], cq[1], cq[2], cq[3]);
        __syncthreads();
        if (tid < 64) {
            int col = c0 + tid;
            if (col < M) {
                float s = 0.f, q = 0.f;
#pragma unroll
                for (int g = 0; g < 16; ++g) { s += As[g][tid]; q += Ws[g][tid]; }
                atomicAdd(&sum[col], s);
                atomicAdd(&ss[col], q);
            }
        }
    }
}

// ---------------------------------------------------------------------------
// Per-column sum & sum-of-squares (used only for the post-stencil layer).
// ---------------------------------------------------------------------------
__global__ void colstats(const float* __restrict__ Y, long long total, int M,
                         float* __restrict__ sum, float* __restrict__ ss) {
    extern __shared__ float sm[];
    float* s1 = sm;
    float* s2 = sm + M;
    for (int f = threadIdx.x; f < 2 * M; f += blockDim.x) sm[f] = 0.f;
    __syncthreads();
    long long stride = (long long)gridDim.x * blockDim.x;
    for (long long i = (long long)blockIdx.x * blockDim.x + threadIdx.x; i < total; i += stride) {
        float v = Y[i];
        int f = (int)(i % M);
        atomicAdd(&s1[f], v);
        atomicAdd(&s2[f], v * v);
    }
    __syncthreads();
    for (int f = threadIdx.x; f < M; f += blockDim.x) {
        atomicAdd(&sum[f], s1[f]);
        atomicAdd(&ss[f], s2[f]);
    }
}

__global__ void bn_finalize(int M, const float* __restrict__ sum, const float* __restrict__ ss,
                            const float* __restrict__ gamma, const float* __restrict__ beta,
                            float* __restrict__ a, float* __restrict__ b, float invN) {
    int f = blockIdx.x * blockDim.x + threadIdx.x;
    if (f < M) {
        float m = sum[f] * invN;
        float v = ss[f] * invN - m * m;
        float sc = gamma[f] * rsqrtf(v + 1e-5f);
        a[f] = sc;
        b[f] = beta[f] - m * sc;
    }
}

// ---------------------------------------------------------------------------
// GMM stencil, float4 over output cols: y2[i,o] = rc[i,o] + (1/deg_i) *
//   sum over 3x3 valid neighbors j, kernels k of gauss[d][k] * t[j, k*44+o].
// ---------------------------------------------------------------------------
__global__ void gmm_stencil4(const float* __restrict__ t, float* __restrict__ rc,
                             const float* __restrict__ mu, const float* __restrict__ sigma) {
    __shared__ float gs[9][3];
    if (threadIdx.x < 27) {
        int d = threadIdx.x / 3, k = threadIdx.x % 3;
        int dx = d / 3 - 1, dy = d % 3 - 1;
        float ex = 0.5f * (float)dx + 0.5f;
        float ey = 0.5f * (float)dy + 0.5f;
        float mx = mu[k * 2 + 0], my = mu[k * 2 + 1];
        float sx = sigma[k * 2 + 0], sy = sigma[k * 2 + 1];
        float q = -0.5f * ((ex - mx) * (ex - mx) / (1e-15f + sx * sx) +
                           (ey - my) * (ey - my) / (1e-15f + sy * sy));
        gs[d][k] = expf(q);
    }
    __syncthreads();
    int idx = blockIdx.x * blockDim.x + threadIdx.x;   // N * 11 threads
    if (idx >= NNODES * 11) return;
    int node = idx / 11;
    int o4 = (idx % 11) << 2;
    int rem = node % (GRID * GRID);
    int ix = rem / GRID, iy = rem % GRID;
    float4 acc = make_float4(0.f, 0.f, 0.f, 0.f);
#pragma unroll
    for (int dx = -1; dx <= 1; ++dx) {
        int jx = ix + dx;
        if (jx < 0 || jx >= GRID) continue;
#pragma unroll
        for (int dy = -1; dy <= 1; ++dy) {
            int jy = iy + dy;
            if (jy < 0 || jy >= GRID) continue;
            int d = (dx + 1) * 3 + (dy + 1);
            const float* tj = t + (size_t)(node + dx * GRID + dy) * 132 + o4;
            float g0 = gs[d][0], g1 = gs[d][1], g2v = gs[d][2];
            float4 t0 = *(const float4*)tj;
            float4 t1 = *(const float4*)(tj + 44);
            float4 t2 = *(const float4*)(tj + 88);
            acc.x += g0 * t0.x + g1 * t1.x + g2v * t2.x;
            acc.y += g0 * t0.y + g1 * t1.y + g2v * t2.y;
            acc.z += g0 * t0.z + g1 * t1.z + g2v * t2.z;
            acc.w += g0 * t0.w + g1 * t1.w + g2v * t2.w;
        }
    }
    int cnt = ((ix > 0) + (ix < GRID - 1) + 1) * ((iy > 0) + (iy < GRID - 1) + 1);
    float inv = 1.f / (float)cnt;
    float* rp = rc + (size_t)node * 44 + o4;
    float4 r = *(const float4*)rp;
    r.x = acc.x * inv + r.x;
    r.y = acc.y * inv + r.y;
    r.z = acc.z * inv + r.z;
    r.w = acc.w * inv + r.w;
    *(float4*)rp = r;
}

// ---------------------------------------------------------------------------
extern "C" void kernel_launch(void* const* d_in, const int* in_sizes, int n_in,
                              void* d_out, int out_size, void* d_ws, size_t ws_size,
                              hipStream_t stream) {
    const float* x      = (const float*)d_in[0];   // (N,128)
    const float* w0     = (const float*)d_in[3];   // (128,102)
    const float* b0     = (const float*)d_in[4];
    const float* gamma0 = (const float*)d_in[5];
    const float* beta0  = (const float*)d_in[6];
    const float* w1     = (const float*)d_in[7];   // (102,73)
    const float* b1     = (const float*)d_in[8];
    const float* gamma1 = (const float*)d_in[9];
    const float* beta1  = (const float*)d_in[10];
    const float* w2     = (const float*)d_in[11];  // (73,44)
    const float* g2     = (const float*)d_in[12];  // (73,132)
    const float* mu2    = (const float*)d_in[13];
    const float* sigma2 = (const float*)d_in[14];
    const float* b2     = (const float*)d_in[15];
    const float* gamma2 = (const float*)d_in[16];
    const float* beta2  = (const float*)d_in[17];
    const float* w3     = (const float*)d_in[18];  // (44,16)
    const float* b3     = (const float*)d_in[19];
    float* out = (float*)d_out;

    const int N = NNODES;
    const float invN = 1.0f / (float)N;

    size_t need = ((size_t)N * (132 + 73 + 44) + 1024) * sizeof(float);
    if (ws_size < need) return;

    float* ws = (float*)d_ws;
    float* bufA = ws;                      // N*132 : y0/h0(102 used), then t(132)
    float* bufB = bufA + (size_t)N * 132;  // N*73  : y1/h1
    float* bufC = bufB + (size_t)N * 73;   // N*44  : r -> y2
    float* stats = bufC + (size_t)N * 44;
    float* sum0 = stats,       *ss0 = sum0 + 102;
    float* sum1 = ss0 + 102,   *ss1 = sum1 + 73;
    float* sum2 = ss1 + 73,    *ss2 = sum2 + 44;
    float* par  = stats + 512;
    float* a0 = par,        *sh0 = a0 + 102;
    float* a1 = sh0 + 102,  *sh1 = a1 + 73;
    float* a2 = sh1 + 73,   *sh2 = a2 + 44;

    zero_buf<<<2, 256, 0, stream>>>(stats, 438);

    const int rowB = N / 64;   // 2304

    // layer 0: y0 = x@w0 + b0, stats fused
    gemm_rt<false, true><<<dim3(2, rowB), 256, 0, stream>>>(
        x, w0, b0, nullptr, nullptr, bufA, sum0, ss0, 128, 102);
    bn_finalize<<<1, 128, 0, stream>>>(102, sum0, ss0, gamma0, beta0, a0, sh0, invN);

    // layer 1: y1 = BN0(y0)@w1 + b1, BN applied on load, stats fused
    gemm_rt<true, true><<<dim3(2, rowB), 256, 0, stream>>>(
        bufA, w1, b1, a0, sh0, bufB, sum1, ss1, 102, 73);
    bn_finalize<<<1, 128, 0, stream>>>(73, sum1, ss1, gamma1, beta1, a1, sh1, invN);

    // layer 2: t = BN1(y1)@g2 ; r = BN1(y1)@w2 + b2
    gemm_rt<true, false><<<dim3(3, rowB), 256, 0, stream>>>(
        bufB, g2, nullptr, a1, sh1, bufA, nullptr, nullptr, 73, 132);
    gemm_rt<true, false><<<dim3(1, rowB), 256, 0, stream>>>(
        bufB, w2, b2, a1, sh1, bufC, nullptr, nullptr, 73, 44);

    // stencil: bufC = r + aggregated(t)
    {
        int tot = N * 11;
        gmm_stencil4<<<(tot + 255) / 256, 256, 0, stream>>>(bufA, bufC, mu2, sigma2);
    }
    colstats<<<2048, 256, 2 * 44 * sizeof(float), stream>>>(bufC, (long long)N * 44, 44, sum2, ss2);
    bn_finalize<<<1, 64, 0, stream>>>(44, sum2, ss2, gamma2, beta2, a2, sh2, invN);

    // output: out = BN2(y2)@w3 + b3
    gemm_rt<true, false><<<dim3(1, rowB), 256, 0, stream>>>(
        bufC, w3, b3, a2, sh2, out, nullptr, nullptr, 44, 16);
}

// Round 4
// 480.723 us; speedup vs baseline: 2.7289x; 1.4162x over previous
//
#include <hip/hip_runtime.h>

#define GRID 48
#define NB 64
#define NNODES (NB * GRID * GRID)   // 147456 = 1152 * 128

typedef __attribute__((ext_vector_type(8))) short short8;
typedef __attribute__((ext_vector_type(4))) float f32x4;

__device__ inline unsigned short f2bf(float f) {
    union { float f; unsigned u; } v; v.f = f;
    unsigned r = v.u + 0x7FFFu + ((v.u >> 16) & 1u);   // round-to-nearest-even
    return (unsigned short)(r >> 16);
}

__global__ void zero_buf(float* __restrict__ p, int n) {
    int i = blockIdx.x * blockDim.x + threadIdx.x;
    if (i < n) p[i] = 0.f;
}

// Pre-convert weight W[K][M] (fp32) -> WT[col0+col][KP] (bf16, k-contiguous,
// zero-padded k>=K). Also fills biasf[col0+col] (0 if bias==null).
__global__ void conv_w(const float* __restrict__ w, const float* __restrict__ bias,
                       unsigned short* __restrict__ wt, float* __restrict__ biasf,
                       int K, int M, int KP, int col0) {
    int idx = blockIdx.x * blockDim.x + threadIdx.x;
    if (idx < M * KP) {
        int col = idx / KP, k = idx - col * KP;
        wt[(size_t)(col0 + col) * KP + k] = (k < K) ? f2bf(w[(size_t)k * M + col]) : 0;
    }
    if (idx < M) biasf[col0 + idx] = bias ? bias[idx] : 0.f;
}

// ---------------------------------------------------------------------------
// MFMA GEMM, whole-K in LDS (K<=128): Y[128 rows][MOUT] = op(A)@W + biasf.
//   op(A)[r][k] = APPLY_IN ? A*ain[k]+bin[k] : A   (prev layer's BN folded in)
//   STATS: per-column sum/sumsq atomics (for this layer's BN).
// Block 256 thr (4 waves); wave w owns rows [32w,32w+32) as 2 row-frags;
// NCF = MP/16 col-frags; mfma_f32_16x16x32_bf16, fp32 accum.
// ---------------------------------------------------------------------------
template<int K, int KP, int MP, int MOUT, bool APPLY_IN, bool STATS>
__global__ __launch_bounds__(256) void gemm_mfma(
    const float* __restrict__ A, const unsigned short* __restrict__ WT,
    const float* __restrict__ biasf,
    const float* __restrict__ ain, const float* __restrict__ bin,
    float* __restrict__ Y, float* __restrict__ sum, float* __restrict__ ss)
{
    constexpr int KS = KP + 8;        // LDS k-stride (bf16 elems); keeps 16B align, breaks bank pow2
    constexpr int NCF = MP / 16;
    __shared__ __align__(16) unsigned short As[128 * KS];
    __shared__ __align__(16) unsigned short Bs[MP * KS];

    const int tid = threadIdx.x;
    const int r0 = blockIdx.x * 128;

    // ---- stage A: 128 x K fp32 -> bf16 (BN folded), coalesced scalar
    for (int g = tid; g < 128 * K; g += 256) {
        int row = g / K, k = g - row * K;
        float v = A[(size_t)(r0 + row) * K + k];
        if (APPLY_IN) v = v * ain[k] + bin[k];
        As[row * KS + k] = f2bf(v);
    }
    if (KP > K) {
        constexpr int PADK = KP - K;
        for (int g = tid; g < 128 * PADK; g += 256) {
            int row = g / PADK, k = K + (g - row * PADK);
            As[row * KS + k] = 0;
        }
    }
    // ---- stage B: copy pre-converted WT (MP x KP, already padded), uint2
    for (int g = tid; g < MP * KP / 4; g += 256) {
        int e = g * 4;
        int col = e / KP, k = e - col * KP;
        *(uint2*)&Bs[col * KS + k] = *(const uint2*)&WT[(size_t)col * KP + k];
    }
    __syncthreads();

    // ---- compute
    const int lane = tid & 63;
    const int wv = tid >> 6;
    const int q = lane >> 4;     // quad
    const int lc = lane & 15;
    const int rowA0 = wv * 32 + lc;

    f32x4 acc[2][NCF];
#pragma unroll
    for (int rf = 0; rf < 2; ++rf)
#pragma unroll
        for (int cf = 0; cf < NCF; ++cf)
            acc[rf][cf] = (f32x4){0.f, 0.f, 0.f, 0.f};

#pragma unroll
    for (int kt = 0; kt < KP / 32; ++kt) {
        const int kb = kt * 32 + q * 8;
        short8 a0 = *(const short8*)&As[rowA0 * KS + kb];
        short8 a1 = *(const short8*)&As[(rowA0 + 16) * KS + kb];
#pragma unroll
        for (int cf = 0; cf < NCF; ++cf) {
            short8 b = *(const short8*)&Bs[(cf * 16 + lc) * KS + kb];
            acc[0][cf] = __builtin_amdgcn_mfma_f32_16x16x32_bf16(a0, b, acc[0][cf], 0, 0, 0);
            acc[1][cf] = __builtin_amdgcn_mfma_f32_16x16x32_bf16(a1, b, acc[1][cf], 0, 0, 0);
        }
    }

    // ---- epilogue: bias, store, fused stats
    float ps[NCF], pq[NCF];
#pragma unroll
    for (int cf = 0; cf < NCF; ++cf) {
        const int col = cf * 16 + lc;
        const float bv = biasf[col];
        float s = 0.f, qq = 0.f;
#pragma unroll
        for (int rf = 0; rf < 2; ++rf)
#pragma unroll
            for (int r = 0; r < 4; ++r) {
                float v = acc[rf][cf][r] + bv;
                int row = r0 + wv * 32 + rf * 16 + q * 4 + r;
                if (col < MOUT) Y[(size_t)row * MOUT + col] = v;
                if (STATS) { s += v; qq += v * v; }
            }
        if (STATS) { ps[cf] = s; pq[cf] = qq; }
    }
    if (STATS) {
        __syncthreads();                 // As/Bs dead, reuse as reduce scratch
        float* red = (float*)As;         // [8][MP]
#pragma unroll
        for (int cf = 0; cf < NCF; ++cf) {
            float s = ps[cf], qq = pq[cf];
            s += __shfl_down(s, 32, 64);  s += __shfl_down(s, 16, 64);
            qq += __shfl_down(qq, 32, 64); qq += __shfl_down(qq, 16, 64);
            if (lane < 16) {
                red[wv * MP + cf * 16 + lane] = s;
                red[(4 + wv) * MP + cf * 16 + lane] = qq;
            }
        }
        __syncthreads();
        if (tid < MOUT) {
            float s = red[tid] + red[MP + tid] + red[2 * MP + tid] + red[3 * MP + tid];
            float qq = red[4 * MP + tid] + red[5 * MP + tid] + red[6 * MP + tid] + red[7 * MP + tid];
            atomicAdd(&sum[tid], s);
            atomicAdd(&ss[tid], qq);
        }
    }
}

__global__ void bn_finalize(int M, const float* __restrict__ sum, const float* __restrict__ ss,
                            const float* __restrict__ gamma, const float* __restrict__ beta,
                            float* __restrict__ a, float* __restrict__ b, float invN) {
    int f = blockIdx.x * blockDim.x + threadIdx.x;
    if (f < M) {
        float m = sum[f] * invN;
        float v = ss[f] * invN - m * m;
        float sc = gamma[f] * rsqrtf(v + 1e-5f);
        a[f] = sc;
        b[f] = beta[f] - m * sc;
    }
}

__global__ void colstats(const float* __restrict__ Y, long long total, int M,
                         float* __restrict__ sum, float* __restrict__ ss) {
    extern __shared__ float sm[];
    float* s1 = sm;
    float* s2 = sm + M;
    for (int f = threadIdx.x; f < 2 * M; f += blockDim.x) sm[f] = 0.f;
    __syncthreads();
    long long stride = (long long)gridDim.x * blockDim.x;
    for (long long i = (long long)blockIdx.x * blockDim.x + threadIdx.x; i < total; i += stride) {
        float v = Y[i];
        int f = (int)(i % M);
        atomicAdd(&s1[f], v);
        atomicAdd(&s2[f], v * v);
    }
    __syncthreads();
    for (int f = threadIdx.x; f < M; f += blockDim.x) {
        atomicAdd(&sum[f], s1[f]);
        atomicAdd(&ss[f], s2[f]);
    }
}

// ---------------------------------------------------------------------------
// GMM stencil over combined TR buffer (width 176: t=cols 0..131, r=132..175):
//   C[i,o] = r[i,o] + (1/deg_i) * sum_{3x3 valid j} sum_k gauss[d][k]*t[j,k*44+o]
// ---------------------------------------------------------------------------
__global__ void gmm_stencil4(const float* __restrict__ TR, float* __restrict__ C,
                             const float* __restrict__ mu, const float* __restrict__ sigma) {
    __shared__ float gs[9][3];
    if (threadIdx.x < 27) {
        int d = threadIdx.x / 3, k = threadIdx.x % 3;
        int dx = d / 3 - 1, dy = d % 3 - 1;
        float ex = 0.5f * (float)dx + 0.5f;
        float ey = 0.5f * (float)dy + 0.5f;
        float mx = mu[k * 2 + 0], my = mu[k * 2 + 1];
        float sx = sigma[k * 2 + 0], sy = sigma[k * 2 + 1];
        float qv = -0.5f * ((ex - mx) * (ex - mx) / (1e-15f + sx * sx) +
                            (ey - my) * (ey - my) / (1e-15f + sy * sy));
        gs[d][k] = expf(qv);
    }
    __syncthreads();
    int idx = blockIdx.x * blockDim.x + threadIdx.x;   // N * 11 threads
    if (idx >= NNODES * 11) return;
    int node = idx / 11;
    int o4 = (idx % 11) << 2;
    int rem = node % (GRID * GRID);
    int ix = rem / GRID, iy = rem % GRID;
    float4 acc = make_float4(0.f, 0.f, 0.f, 0.f);
#pragma unroll
    for (int dx = -1; dx <= 1; ++dx) {
        int jx = ix + dx;
        if (jx < 0 || jx >= GRID) continue;
#pragma unroll
        for (int dy = -1; dy <= 1; ++dy) {
            int jy = iy + dy;
            if (jy < 0 || jy >= GRID) continue;
            int d = (dx + 1) * 3 + (dy + 1);
            const float* tj = TR + (size_t)(node + dx * GRID + dy) * 176 + o4;
            float g0 = gs[d][0], g1 = gs[d][1], g2v = gs[d][2];
            float4 t0 = *(const float4*)tj;
            float4 t1 = *(const float4*)(tj + 44);
            float4 t2 = *(const float4*)(tj + 88);
            acc.x += g0 * t0.x + g1 * t1.x + g2v * t2.x;
            acc.y += g0 * t0.y + g1 * t1.y + g2v * t2.y;
            acc.z += g0 * t0.z + g1 * t1.z + g2v * t2.z;
            acc.w += g0 * t0.w + g1 * t1.w + g2v * t2.w;
        }
    }
    int cnt = ((ix > 0) + (ix < GRID - 1) + 1) * ((iy > 0) + (iy < GRID - 1) + 1);
    float inv = 1.f / (float)cnt;
    const float* rp = TR + (size_t)node * 176 + 132 + o4;
    float4 r = *(const float4*)rp;
    float4 o;
    o.x = acc.x * inv + r.x;
    o.y = acc.y * inv + r.y;
    o.z = acc.z * inv + r.z;
    o.w = acc.w * inv + r.w;
    *(float4*)&C[(size_t)node * 44 + o4] = o;
}

// ---------------------------------------------------------------------------
extern "C" void kernel_launch(void* const* d_in, const int* in_sizes, int n_in,
                              void* d_out, int out_size, void* d_ws, size_t ws_size,
                              hipStream_t stream) {
    const float* x      = (const float*)d_in[0];   // (N,128)
    const float* w0     = (const float*)d_in[3];   // (128,102)
    const float* b0     = (const float*)d_in[4];
    const float* gamma0 = (const float*)d_in[5];
    const float* beta0  = (const float*)d_in[6];
    const float* w1     = (const float*)d_in[7];   // (102,73)
    const float* b1     = (const float*)d_in[8];
    const float* gamma1 = (const float*)d_in[9];
    const float* beta1  = (const float*)d_in[10];
    const float* w2     = (const float*)d_in[11];  // (73,44)
    const float* g2     = (const float*)d_in[12];  // (73,132)
    const float* mu2    = (const float*)d_in[13];
    const float* sigma2 = (const float*)d_in[14];
    const float* b2     = (const float*)d_in[15];
    const float* gamma2 = (const float*)d_in[16];
    const float* beta2  = (const float*)d_in[17];
    const float* w3     = (const float*)d_in[18];  // (44,16)
    const float* b3     = (const float*)d_in[19];
    float* out = (float*)d_out;

    const int N = NNODES;
    const float invN = 1.0f / (float)N;

    // ws layout (floats): Y1 [0,73N) ; C [0,44N) after Y1 dead ;
    // Y0 [73N,175N) ; TR [73N,249N) after Y0 dead ; smalls at 249N.
    const size_t tailN = (size_t)N * 249;
    size_t need = (tailN + 24000) * sizeof(float);
    if (ws_size < need) return;

    float* ws = (float*)d_ws;
    float* bufY1 = ws;                       // N*73
    float* bufC  = ws;                       // N*44 (aliases Y1; Y1 dead by then)
    float* bufY0 = ws + (size_t)N * 73;      // N*102
    float* bufTR = ws + (size_t)N * 73;      // N*176 (aliases Y0; Y0 dead by then)
    float* tail  = ws + tailN;
    float* sum0 = tail,        *ss0 = sum0 + 102;
    float* sum1 = ss0 + 102,   *ss1 = sum1 + 73;
    float* sum2 = ss1 + 73,    *ss2 = sum2 + 44;
    float* par  = tail + 512;
    float* a0 = par,        *sh0 = a0 + 102;
    float* a1 = sh0 + 102,  *sh1 = a1 + 73;
    float* a2 = sh1 + 73,   *sh2 = a2 + 44;
    unsigned short* wt0 = (unsigned short*)(tail + 1024);   // 112*128
    unsigned short* wt1 = wt0 + 112 * 128;                  // 80*128
    unsigned short* wt2 = wt1 + 80 * 128;                   // 176*96
    unsigned short* wt3 = wt2 + 176 * 96;                   // 16*64
    float* biasf0 = tail + 1024 + 21248;     // 112
    float* biasf1 = biasf0 + 112;            // 80
    float* biasf2 = biasf1 + 80;             // 176
    float* biasf3 = biasf2 + 176;            // 16

    // zero stats + weight/bias region (incl. padding)
    zero_buf<<<(1024 + 21248 + 384 + 255) / 256, 256, 0, stream>>>(tail, 1024 + 21248 + 384);

    // pre-convert weights to bf16 [col][KP]
    conv_w<<<(102 * 128 + 255) / 256, 256, 0, stream>>>(w0, b0, wt0, biasf0, 128, 102, 128, 0);
    conv_w<<<(73 * 128 + 255) / 256, 256, 0, stream>>>(w1, b1, wt1, biasf1, 102, 73, 128, 0);
    conv_w<<<(132 * 96 + 255) / 256, 256, 0, stream>>>(g2, nullptr, wt2, biasf2, 73, 132, 96, 0);
    conv_w<<<(44 * 96 + 255) / 256, 256, 0, stream>>>(w2, b2, wt2, biasf2, 73, 44, 96, 132);
    conv_w<<<(16 * 64 + 255) / 256, 256, 0, stream>>>(w3, b3, wt3, biasf3, 44, 16, 64, 0);

    const int nblk = N / 128;   // 1152

    // L0: y0 = x@w0+b0, stats fused
    gemm_mfma<128, 128, 112, 102, false, true><<<nblk, 256, 0, stream>>>(
        x, wt0, biasf0, nullptr, nullptr, bufY0, sum0, ss0);
    bn_finalize<<<1, 128, 0, stream>>>(102, sum0, ss0, gamma0, beta0, a0, sh0, invN);

    // L1: y1 = BN0(y0)@w1+b1, stats fused
    gemm_mfma<102, 128, 80, 73, true, true><<<nblk, 256, 0, stream>>>(
        bufY0, wt1, biasf1, a0, sh0, bufY1, sum1, ss1);
    bn_finalize<<<1, 128, 0, stream>>>(73, sum1, ss1, gamma1, beta1, a1, sh1, invN);

    // L2 fused: TR = BN1(y1) @ [g2 | w2] (+[0|b2]), width 176
    gemm_mfma<73, 96, 176, 176, true, false><<<nblk, 256, 0, stream>>>(
        bufY1, wt2, biasf2, a1, sh1, bufTR, nullptr, nullptr);

    // stencil: C = r + aggregated(t)
    gmm_stencil4<<<(N * 11 + 255) / 256, 256, 0, stream>>>(bufTR, bufC, mu2, sigma2);

    colstats<<<2048, 256, 2 * 44 * sizeof(float), stream>>>(bufC, (long long)N * 44, 44, sum2, ss2);
    bn_finalize<<<1, 64, 0, stream>>>(44, sum2, ss2, gamma2, beta2, a2, sh2, invN);

    // L3: out = BN2(C)@w3 + b3
    gemm_mfma<44, 64, 16, 16, true, false><<<nblk, 256, 0, stream>>>(
        bufC, wt3, biasf3, a2, sh2, out, nullptr, nullptr);
}

// Round 5
// 380.212 us; speedup vs baseline: 3.4503x; 1.2644x over previous
//
#include <hip/hip_runtime.h>

#define GRID 48
#define NB 64
#define NNODES (NB * GRID * GRID)   // 147456 = 2304 * 64

typedef __attribute__((ext_vector_type(8))) short short8;
typedef __attribute__((ext_vector_type(4))) float f32x4;
typedef __attribute__((ext_vector_type(4))) unsigned short ushort4v;

__device__ inline unsigned short f2bf(float f) {
    union { float f; unsigned u; } v; v.f = f;
    unsigned r = v.u + 0x7FFFu + ((v.u >> 16) & 1u);
    return (unsigned short)(r >> 16);
}
__device__ inline float bf2f(unsigned short h) {
    union { unsigned u; float f; } v; v.u = ((unsigned)h) << 16;
    return v.f;
}

// ---------------------------------------------------------------------------
// prep: all weight bf16 conversion ([col][KP], k-contig, zero-padded),
// biases (padded), stats zeroing — single kernel, replaces 6 dispatches.
// ---------------------------------------------------------------------------
__global__ void prep(const float* __restrict__ w0, const float* __restrict__ b0,
                     const float* __restrict__ w1, const float* __restrict__ b1,
                     const float* __restrict__ g2, const float* __restrict__ w2,
                     const float* __restrict__ b2, const float* __restrict__ w3,
                     const float* __restrict__ b3,
                     unsigned short* __restrict__ wt0, unsigned short* __restrict__ wt1,
                     unsigned short* __restrict__ wt2, unsigned short* __restrict__ wt3,
                     float* __restrict__ biasf0, float* __restrict__ biasf1,
                     float* __restrict__ biasf2, float* __restrict__ biasf3,
                     float* __restrict__ statz) {
    int id = blockIdx.x * 256 + threadIdx.x;
    if (id < 14336) {                         // wt0: 112 cols x 128 k
        int col = id >> 7, k = id & 127;
        wt0[id] = (col < 102) ? f2bf(w0[k * 102 + col]) : (unsigned short)0;
    } else if (id < 24576) {                  // wt1: 80 x 128
        int e = id - 14336; int col = e >> 7, k = e & 127;
        wt1[e] = (col < 73 && k < 102) ? f2bf(w1[k * 73 + col]) : (unsigned short)0;
    } else if (id < 41472) {                  // wt2: 176 x 96 (g2 | w2)
        int e = id - 24576; int col = e / 96, k = e - (e / 96) * 96;
        unsigned short v = 0;
        if (k < 73) v = (col < 132) ? f2bf(g2[k * 132 + col]) : f2bf(w2[k * 44 + (col - 132)]);
        wt2[e] = v;
    } else if (id < 42496) {                  // wt3: 16 x 64
        int e = id - 41472; int col = e >> 6, k = e & 63;
        wt3[e] = (k < 44) ? f2bf(w3[k * 16 + col]) : (unsigned short)0;
    } else if (id < 42608) { int c = id - 42496; biasf0[c] = (c < 102) ? b0[c] : 0.f; }
    else if (id < 42688) { int c = id - 42608; biasf1[c] = (c < 73) ? b1[c] : 0.f; }
    else if (id < 42864) { int c = id - 42688; biasf2[c] = (c < 132) ? 0.f : b2[c - 132]; }
    else if (id < 42880) { int c = id - 42864; biasf3[c] = b3[c]; }
    else if (id < 43264) { statz[id - 42880] = 0.f; }
}

// ---------------------------------------------------------------------------
// MFMA GEMM, whole-K in LDS, 64 rows/block, 4 waves (wave = 16-row frag).
// BN of the PREVIOUS layer is folded into B:  y = x·(a∘W) + (bias + b·W).
//   BNSRC 0: none; 1: (a,b) from (sum,ss,gamma,beta); 2: precomputed (a,b).
// STATS: this layer's column sum/sumsq via block-reduce + global atomics.
// ---------------------------------------------------------------------------
template<int K, int KP, int MP, int MOUT, int PREVM, int BNSRC,
         bool STATS, bool OUTBF, bool ABF16>
__global__ __launch_bounds__(256) void gemm64(
    const void* __restrict__ Ain, const unsigned short* __restrict__ WT,
    const float* __restrict__ biasf,
    const float* __restrict__ q0, const float* __restrict__ q1,
    const float* __restrict__ q2, const float* __restrict__ q3,
    float invN, void* __restrict__ Yout,
    float* __restrict__ sum, float* __restrict__ ss)
{
    constexpr int KS = KP + 8;    // LDS k-stride: keeps 16B align, 2-way banks max
    constexpr int NCF = MP / 16;
    __shared__ __align__(16) unsigned short As[64 * KS];
    __shared__ __align__(16) unsigned short Bs[MP * KS];
    __shared__ __align__(16) float bnA[KP];
    __shared__ __align__(16) float bnB[KP];
    __shared__ float biasv[MP];

    const int tid = threadIdx.x;
    const int r0 = blockIdx.x * 64;

    if (BNSRC == 1) {
        if (tid < KP) {
            float a = 0.f, b = 0.f;
            if (tid < PREVM) {
                float m = q0[tid] * invN;
                float v = q1[tid] * invN - m * m;
                float sc = q2[tid] * rsqrtf(v + 1e-5f);
                a = sc; b = q3[tid] - m * sc;
            }
            bnA[tid] = a; bnB[tid] = b;
        }
        __syncthreads();
    } else if (BNSRC == 2) {
        if (tid < KP) { bnA[tid] = q0[tid]; bnB[tid] = q1[tid]; }
        __syncthreads();
    }

    // ---- stage A (pure copy / pure convert; BN lives in B)
    if (ABF16) {
        const unsigned short* A = (const unsigned short*)Ain;
        constexpr int UPR = K / 8;
        for (int g = tid; g < 64 * UPR; g += 256) {
            int row = g / UPR, u = g - row * UPR;
            *(uint4*)&As[row * KS + u * 8] =
                *(const uint4*)&A[(size_t)(r0 + row) * K + u * 8];
        }
    } else {
        const float* A = (const float*)Ain;
        constexpr int UPR = K / 4;
        for (int g = tid; g < 64 * UPR; g += 256) {
            int row = g / UPR, u = g - row * UPR;
            float4 v = *(const float4*)&A[(size_t)(r0 + row) * K + u * 4];
            unsigned lo = (unsigned)f2bf(v.x) | ((unsigned)f2bf(v.y) << 16);
            unsigned hi = (unsigned)f2bf(v.z) | ((unsigned)f2bf(v.w) << 16);
            *(uint2*)&As[row * KS + u * 4] = make_uint2(lo, hi);
        }
    }
    if constexpr (KP > K) {
        constexpr int PADU = (KP - K) / 2;   // uint (2-short) units
        for (int g = tid; g < 64 * PADU; g += 256) {
            int row = g / PADU, u = g - row * PADU;
            *(unsigned*)&As[row * KS + K + u * 2] = 0u;
        }
    }
    // ---- stage B (scaled by bnA when BN folded)
    {
        constexpr int UPC = KP / 8;
        for (int g = tid; g < MP * UPC; g += 256) {
            int col = g / UPC, u = g - col * UPC;
            uint4 w = *(const uint4*)&WT[(size_t)col * KP + u * 8];
            if (BNSRC != 0) {
                float4 s0 = *(const float4*)&bnA[u * 8];
                float4 s1 = *(const float4*)&bnA[u * 8 + 4];
                float sc[8] = {s0.x, s0.y, s0.z, s0.w, s1.x, s1.y, s1.z, s1.w};
                unsigned r[4] = {w.x, w.y, w.z, w.w};
                uint4 o; unsigned* op = (unsigned*)&o;
#pragma unroll
                for (int p = 0; p < 4; ++p) {
                    float lo = bf2f((unsigned short)(r[p] & 0xFFFFu)) * sc[2 * p];
                    float hi = bf2f((unsigned short)(r[p] >> 16)) * sc[2 * p + 1];
                    op[p] = (unsigned)f2bf(lo) | ((unsigned)f2bf(hi) << 16);
                }
                *(uint4*)&Bs[col * KS + u * 8] = o;
            } else {
                *(uint4*)&Bs[col * KS + u * 8] = w;
            }
        }
    }
    // ---- biasv[c] = bias[c] + sum_k bnB[k]*W[k][c]
    for (int c = tid; c < MP; c += 256) {
        float b = biasf[c];
        if (BNSRC != 0) {
            float accb = 0.f;
            for (int k = 0; k < K; ++k)
                accb += bf2f(WT[(size_t)c * KP + k]) * bnB[k];
            b += accb;
        }
        biasv[c] = b;
    }
    __syncthreads();

    // ---- compute
    const int lane = tid & 63;
    const int wv = tid >> 6;
    const int qd = lane >> 4;
    const int lc = lane & 15;

    f32x4 acc[NCF];
#pragma unroll
    for (int cf = 0; cf < NCF; ++cf) acc[cf] = (f32x4){0.f, 0.f, 0.f, 0.f};

#pragma unroll
    for (int kt = 0; kt < KP / 32; ++kt) {
        const int kb = kt * 32 + qd * 8;
        short8 a = *(const short8*)&As[(wv * 16 + lc) * KS + kb];
#pragma unroll
        for (int cf = 0; cf < NCF; ++cf) {
            short8 b = *(const short8*)&Bs[(cf * 16 + lc) * KS + kb];
            acc[cf] = __builtin_amdgcn_mfma_f32_16x16x32_bf16(a, b, acc[cf], 0, 0, 0);
        }
    }

    // ---- epilogue
    float cs[NCF], cq[NCF];
#pragma unroll
    for (int cf = 0; cf < NCF; ++cf) {
        const int col = cf * 16 + lc;
        const float bv = biasv[col];
        float s = 0.f, qq = 0.f;
#pragma unroll
        for (int rr = 0; rr < 4; ++rr) {
            float v = acc[cf][rr] + bv;
            int row = r0 + wv * 16 + qd * 4 + rr;
            if (OUTBF) ((unsigned short*)Yout)[(size_t)row * MP + col] = f2bf(v);
            else       ((float*)Yout)[(size_t)row * MP + col] = v;
            if (STATS) { s += v; qq += v * v; }
        }
        cs[cf] = s; cq[cf] = qq;
    }
    if (STATS) {
        __syncthreads();                  // As dead -> reduce scratch
        float* red = (float*)As;          // [4][MP] sums, [4][MP] sumsq
        float* redq = red + 4 * MP;
#pragma unroll
        for (int cf = 0; cf < NCF; ++cf) {
            float s = cs[cf], qq = cq[cf];
            s += __shfl_down(s, 32, 64); s += __shfl_down(s, 16, 64);
            qq += __shfl_down(qq, 32, 64); qq += __shfl_down(qq, 16, 64);
            if (lane < 16) {
                red[wv * MP + cf * 16 + lane] = s;
                redq[wv * MP + cf * 16 + lane] = qq;
            }
        }
        __syncthreads();
        if (tid < MOUT) {
            float s = red[tid] + red[MP + tid] + red[2 * MP + tid] + red[3 * MP + tid];
            float qq = redq[tid] + redq[MP + tid] + redq[2 * MP + tid] + redq[3 * MP + tid];
            atomicAdd(&sum[tid], s);
            atomicAdd(&ss[tid], qq);
        }
    }
}

// ---------------------------------------------------------------------------
// GMM stencil (bf16 TR in, fp32 C out) + fused BN2 stats as per-block
// contention-free partials. Grid 704x256: total threads = 11*16384, so each
// thread's column-group og = base%11 is CONSTANT across its 9 elements.
// ---------------------------------------------------------------------------
__global__ __launch_bounds__(256) void gmm_stencil(
    const unsigned short* __restrict__ TR, float* __restrict__ C,
    const float* __restrict__ mu, const float* __restrict__ sigma,
    float* __restrict__ partial)
{
    __shared__ float gs[9][3];
    __shared__ float red[88];
    const int tid = threadIdx.x;
    if (tid < 88) red[tid] = 0.f;
    if (tid < 27) {
        int d = tid / 3, k = tid - (tid / 3) * 3;
        int dx = d / 3 - 1, dy = d % 3 - 1;
        float ex = 0.5f * dx + 0.5f, ey = 0.5f * dy + 0.5f;
        float mx = mu[k * 2], my = mu[k * 2 + 1];
        float sx = sigma[k * 2], sy = sigma[k * 2 + 1];
        gs[d][k] = expf(-0.5f * ((ex - mx) * (ex - mx) / (1e-15f + sx * sx) +
                                 (ey - my) * (ey - my) / (1e-15f + sy * sy)));
    }
    __syncthreads();

    const int base = blockIdx.x * 256 + tid;
    const int og = base % 11;
    const int node0 = base / 11;
    const int c0 = og * 4;

    float4 s4 = make_float4(0, 0, 0, 0), q4 = make_float4(0, 0, 0, 0);

    for (int it = 0; it < 9; ++it) {
        int node = node0 + it * 16384;
        int rem = node % (GRID * GRID);
        int ix = rem / GRID, iy = rem - (rem / GRID) * GRID;
        float ax = 0, ay = 0, az = 0, aw = 0;
#pragma unroll
        for (int dx = -1; dx <= 1; ++dx) {
            int jx = ix + dx;
            if (jx < 0 || jx >= GRID) continue;
#pragma unroll
            for (int dy = -1; dy <= 1; ++dy) {
                int jy = iy + dy;
                if (jy < 0 || jy >= GRID) continue;
                int d = (dx + 1) * 3 + (dy + 1);
                const unsigned short* tj = TR + (size_t)(node + dx * GRID + dy) * 176 + c0;
                float g0 = gs[d][0], g1 = gs[d][1], g2v = gs[d][2];
                ushort4v t0 = *(const ushort4v*)tj;
                ushort4v t1 = *(const ushort4v*)(tj + 44);
                ushort4v t2 = *(const ushort4v*)(tj + 88);
                ax += g0 * bf2f(t0.x) + g1 * bf2f(t1.x) + g2v * bf2f(t2.x);
                ay += g0 * bf2f(t0.y) + g1 * bf2f(t1.y) + g2v * bf2f(t2.y);
                az += g0 * bf2f(t0.z) + g1 * bf2f(t1.z) + g2v * bf2f(t2.z);
                aw += g0 * bf2f(t0.w) + g1 * bf2f(t1.w) + g2v * bf2f(t2.w);
            }
        }
        int cnt = ((ix > 0) + (ix < GRID - 1) + 1) * ((iy > 0) + (iy < GRID - 1) + 1);
        float inv = 1.f / (float)cnt;
        const unsigned short* rp = TR + (size_t)node * 176 + 132 + c0;
        ushort4v rv = *(const ushort4v*)rp;
        float4 o;
        o.x = ax * inv + bf2f(rv.x);
        o.y = ay * inv + bf2f(rv.y);
        o.z = az * inv + bf2f(rv.z);
        o.w = aw * inv + bf2f(rv.w);
        *(float4*)&C[(size_t)node * 44 + c0] = o;
        s4.x += o.x; s4.y += o.y; s4.z += o.z; s4.w += o.w;
        q4.x += o.x * o.x; q4.y += o.y * o.y; q4.z += o.z * o.z; q4.w += o.w * o.w;
    }
    atomicAdd(&red[c0 + 0], s4.x); atomicAdd(&red[c0 + 1], s4.y);
    atomicAdd(&red[c0 + 2], s4.z); atomicAdd(&red[c0 + 3], s4.w);
    atomicAdd(&red[44 + c0 + 0], q4.x); atomicAdd(&red[44 + c0 + 1], q4.y);
    atomicAdd(&red[44 + c0 + 2], q4.z); atomicAdd(&red[44 + c0 + 3], q4.w);
    __syncthreads();
    if (tid < 88) partial[(size_t)blockIdx.x * 88 + tid] = red[tid];
}

// Reduce 704 partials -> BN2 scale/shift (padded to 64 with zeros).
__global__ __launch_bounds__(704) void reduce_bn2(
    const float* __restrict__ partial, const float* __restrict__ gamma,
    const float* __restrict__ beta, float* __restrict__ a2p,
    float* __restrict__ sh2p, float invN)
{
    __shared__ float part[8][88];
    __shared__ float tot[88];
    const int tid = threadIdx.x;
    const int c = tid % 88, rg = tid / 88;
    float s = 0.f;
    for (int r = rg; r < 704; r += 8) s += partial[(size_t)r * 88 + c];
    part[rg][c] = s;
    __syncthreads();
    if (tid < 88) {
        float t = 0.f;
#pragma unroll
        for (int g = 0; g < 8; ++g) t += part[g][tid];
        tot[tid] = t;
    }
    __syncthreads();
    if (tid < 64) {
        float a = 0.f, b = 0.f;
        if (tid < 44) {
            float m = tot[tid] * invN;
            float v = tot[44 + tid] * invN - m * m;
            float sc = gamma[tid] * rsqrtf(v + 1e-5f);
            a = sc; b = beta[tid] - m * sc;
        }
        a2p[tid] = a; sh2p[tid] = b;
    }
}

// ---------------------------------------------------------------------------
extern "C" void kernel_launch(void* const* d_in, const int* in_sizes, int n_in,
                              void* d_out, int out_size, void* d_ws, size_t ws_size,
                              hipStream_t stream) {
    const float* x      = (const float*)d_in[0];
    const float* w0     = (const float*)d_in[3];
    const float* b0     = (const float*)d_in[4];
    const float* gamma0 = (const float*)d_in[5];
    const float* beta0  = (const float*)d_in[6];
    const float* w1     = (const float*)d_in[7];
    const float* b1     = (const float*)d_in[8];
    const float* gamma1 = (const float*)d_in[9];
    const float* beta1  = (const float*)d_in[10];
    const float* w2     = (const float*)d_in[11];
    const float* g2     = (const float*)d_in[12];
    const float* mu2    = (const float*)d_in[13];
    const float* sigma2 = (const float*)d_in[14];
    const float* b2     = (const float*)d_in[15];
    const float* gamma2 = (const float*)d_in[16];
    const float* beta2  = (const float*)d_in[17];
    const float* w3     = (const float*)d_in[18];
    const float* b3     = (const float*)d_in[19];
    float* out = (float*)d_out;

    const int N = NNODES;
    const float invN = 1.0f / (float)N;

    // Layout (float units):
    //   [0,44N)      : Y1 bf16 (40N eq) then C fp32 (44N)     — lifetimes disjoint
    //   [44N,132N)   : Y0 bf16 (56N eq) then TR bf16 (88N eq) — lifetimes disjoint
    //   [132N, ...)  : stats/bias/partials/bf16 weights
    const size_t tailOff = (size_t)N * 132;
    size_t need = (tailOff + 84096 + 64) * sizeof(float);
    if (ws_size < need) return;

    float* ws = (float*)d_ws;
    unsigned short* bufY1 = (unsigned short*)ws;                       // N*80 bf16
    float*          bufC  = ws;                                        // N*44 f32
    unsigned short* bufY0 = (unsigned short*)(ws + (size_t)N * 44);    // N*112 bf16
    unsigned short* bufTR = (unsigned short*)(ws + (size_t)N * 44);    // N*176 bf16

    float* tail = ws + tailOff;
    float* sum0 = tail;            // 112
    float* ss0  = tail + 112;      // 112
    float* sum1 = tail + 224;      // 80
    float* ss1  = tail + 304;      // 80
    float* a2p  = tail + 384;      // 64
    float* sh2p = tail + 448;      // 64
    float* biasf0 = tail + 512;    // 112
    float* biasf1 = tail + 624;    // 80
    float* biasf2 = tail + 704;    // 176
    float* biasf3 = tail + 880;    // 16
    float* partial = tail + 896;   // 704*88 = 61952
    unsigned short* wt0 = (unsigned short*)(tail + 62848);  // 112*128
    unsigned short* wt1 = wt0 + 112 * 128;                  // 80*128
    unsigned short* wt2 = wt1 + 80 * 128;                   // 176*96
    unsigned short* wt3 = wt2 + 176 * 96;                   // 16*64

    prep<<<169, 256, 0, stream>>>(w0, b0, w1, b1, g2, w2, b2, w3, b3,
                                  wt0, wt1, wt2, wt3,
                                  biasf0, biasf1, biasf2, biasf3, tail);

    const int nblk = N / 64;   // 2304

    // L0: Y0 = x @ w0 + b0 (bf16 out, stats fused)
    gemm64<128, 128, 112, 102, 0, 0, true, true, false><<<nblk, 256, 0, stream>>>(
        x, wt0, biasf0, nullptr, nullptr, nullptr, nullptr, invN, bufY0, sum0, ss0);

    // L1: Y1 = BN0(Y0) @ w1 + b1 (BN folded into B; stats fused)
    gemm64<112, 128, 80, 73, 102, 1, true, true, true><<<nblk, 256, 0, stream>>>(
        bufY0, wt1, biasf1, sum0, ss0, gamma0, beta0, invN, bufY1, sum1, ss1);

    // L2: TR = BN1(Y1) @ [g2 | w2] (+[0|b2])
    gemm64<80, 96, 176, 176, 73, 1, false, true, true><<<nblk, 256, 0, stream>>>(
        bufY1, wt2, biasf2, sum1, ss1, gamma1, beta1, invN, bufTR, nullptr, nullptr);

    // stencil: C = r + agg(t)/deg ; BN2 stat partials fused
    gmm_stencil<<<704, 256, 0, stream>>>(bufTR, bufC, mu2, sigma2, partial);
    reduce_bn2<<<1, 704, 0, stream>>>(partial, gamma2, beta2, a2p, sh2p, invN);

    // L3: out = BN2(C) @ w3 + b3 (fp32 out)
    gemm64<44, 64, 16, 16, 44, 2, false, false, false><<<nblk, 256, 0, stream>>>(
        bufC, wt3, biasf3, a2p, sh2p, nullptr, nullptr, invN, out, nullptr, nullptr);
}

// Round 7
// 288.549 us; speedup vs baseline: 4.5464x; 1.3177x over previous
//
#include <hip/hip_runtime.h>

#define GRIDW 48
#define NNODES 147456
#define NTILES 2304   // NNODES/64
#define GB 512        // persistent GEMM grid

typedef __attribute__((ext_vector_type(8))) short short8;
typedef __attribute__((ext_vector_type(4))) float f32x4;
typedef __attribute__((ext_vector_type(4))) unsigned short ushort4v;

__device__ inline unsigned short f2bf(float f) {
    union { float f; unsigned u; } v; v.f = f;
    unsigned r = v.u + 0x7FFFu + ((v.u >> 16) & 1u);
    return (unsigned short)(r >> 16);
}
__device__ inline float bf2f(unsigned short h) {
    union { unsigned u; float f; } v; v.u = ((unsigned)h) << 16;
    return v.f;
}

// ---------------------------------------------------------------------------
// prep: weights->bf16 [col][KP] (k-contig, zero-padded), padded biases,
// zero stats. One kernel.
// ---------------------------------------------------------------------------
__global__ void prep(const float* __restrict__ w0, const float* __restrict__ b0,
                     const float* __restrict__ w1, const float* __restrict__ b1,
                     const float* __restrict__ g2, const float* __restrict__ w2,
                     const float* __restrict__ b2, const float* __restrict__ w3,
                     const float* __restrict__ b3,
                     unsigned short* __restrict__ wt0, unsigned short* __restrict__ wt1,
                     unsigned short* __restrict__ wt2, unsigned short* __restrict__ wt3,
                     float* __restrict__ biasf0, float* __restrict__ biasf1,
                     float* __restrict__ biasf2, float* __restrict__ biasf3,
                     float* __restrict__ statz) {
    int id = blockIdx.x * 256 + threadIdx.x;
    if (id < 14336) {                         // wt0: 112 cols x 128 k
        int col = id >> 7, k = id & 127;
        wt0[id] = (col < 102) ? f2bf(w0[k * 102 + col]) : (unsigned short)0;
    } else if (id < 24576) {                  // wt1: 80 x 128
        int e = id - 14336; int col = e >> 7, k = e & 127;
        wt1[e] = (col < 73 && k < 102) ? f2bf(w1[k * 73 + col]) : (unsigned short)0;
    } else if (id < 41472) {                  // wt2: 176 x 96 (g2 | w2)
        int e = id - 24576; int col = e / 96, k = e - (e / 96) * 96;
        unsigned short v = 0;
        if (k < 73) v = (col < 132) ? f2bf(g2[k * 132 + col]) : f2bf(w2[k * 44 + (col - 132)]);
        wt2[e] = v;
    } else if (id < 42496) {                  // wt3: 16 x 64
        int e = id - 41472; int col = e >> 6, k = e & 63;
        wt3[e] = (k < 44) ? f2bf(w3[k * 16 + col]) : (unsigned short)0;
    } else if (id < 42608) { int c = id - 42496; biasf0[c] = (c < 102) ? b0[c] : 0.f; }
    else if (id < 42688) { int c = id - 42608; biasf1[c] = (c < 73) ? b1[c] : 0.f; }
    else if (id < 42864) { int c = id - 42688; biasf2[c] = (c < 132) ? 0.f : b2[c - 132]; }
    else if (id < 42880) { int c = id - 42864; biasf3[c] = b3[c]; }
    else if (id < 43264) { statz[id - 42880] = 0.f; }
}

// ---------------------------------------------------------------------------
// Persistent MFMA GEMM, whole-K in LDS, 64-row tiles grid-strided over a
// 512-block grid, double-buffered A with register prefetch (loads for tile
// t+1 issued before the barrier of tile t). BN of the previous layer is
// applied on the A side during the LDS commit.
//   BNSRC 0: none; 1: from (sum,ss,gamma,beta); 2: precomputed (a,b).
// ---------------------------------------------------------------------------
template<int K, int KP, int MP, int MOUT, int PREVM, int BNSRC,
         bool STATS, bool OUTBF, bool ABF16>
__global__ __launch_bounds__(256) void gemm_p(
    const void* __restrict__ Ain, const unsigned short* __restrict__ WT,
    const float* __restrict__ biasf,
    const float* __restrict__ q0, const float* __restrict__ q1,
    const float* __restrict__ q2, const float* __restrict__ q3,
    float invN, void* __restrict__ Yout,
    float* __restrict__ sumO, float* __restrict__ ssO)
{
    constexpr int KS = KP + 8;              // LDS k-stride (16B-aligned rows)
    constexpr int NCF = MP / 16;
    constexpr int UPR = ABF16 ? (K / 8) : (K / 4);   // 16B units per row
    constexpr int TOT = 64 * UPR;
    constexpr int NLD = (TOT + 255) / 256;
    __shared__ __align__(16) unsigned short As[2][64 * KS];
    __shared__ __align__(16) unsigned short Bs[MP * KS];
    __shared__ float bnA[KP], bnB[KP];

    const int tid = threadIdx.x;
    const int lane = tid & 63, wv = tid >> 6, qd = lane >> 4, lc = lane & 15;

    // BN params of previous layer
    if (BNSRC == 1) {
        if (tid < KP) {
            float a = 0.f, b = 0.f;
            if (tid < PREVM) {
                float m = q0[tid] * invN;
                float v = q1[tid] * invN - m * m;
                float sc = q2[tid] * rsqrtf(v + 1e-5f);
                a = sc; b = q3[tid] - m * sc;
            }
            bnA[tid] = a; bnB[tid] = b;
        }
    } else if (BNSRC == 2) {
        if (tid < KP) {
            bnA[tid] = (tid < PREVM) ? q0[tid] : 0.f;
            bnB[tid] = (tid < PREVM) ? q1[tid] : 0.f;
        }
    }
    // stage B once (pure copy of pre-converted bf16 [col][KP])
    for (int g = tid; g < MP * (KP / 8); g += 256) {
        int col = g / (KP / 8), u = g - col * (KP / 8);
        *(uint4*)&Bs[col * KS + u * 8] = *(const uint4*)&WT[(size_t)col * KP + u * 8];
    }
    // zero the k-pad region of BOTH A buffers (persists across tiles)
    if constexpr (KP > K) {
        constexpr int PADU = (KP - K) / 2;
        for (int g = tid; g < 64 * PADU; g += 256) {
            int row = g / PADU, u = g - row * PADU;
            *(unsigned*)&As[0][row * KS + K + u * 2] = 0u;
            *(unsigned*)&As[1][row * KS + K + u * 2] = 0u;
        }
    }

    float bvr[NCF];
#pragma unroll
    for (int cf = 0; cf < NCF; ++cf) bvr[cf] = biasf[cf * 16 + lc];

    float cs[NCF], cq[NCF];
    if (STATS) {
#pragma unroll
        for (int cf = 0; cf < NCF; ++cf) { cs[cf] = 0.f; cq[cf] = 0.f; }
    }

    uint4 pfb[NLD];
    float4 pff[NLD];

    int t = blockIdx.x;
    // preload first tile
#pragma unroll
    for (int i = 0; i < NLD; ++i) {
        int g = tid + 256 * i;
        if (g < TOT) {
            if constexpr (ABF16)
                pfb[i] = *(const uint4*)((const unsigned short*)Ain + (size_t)t * 64 * K + g * 8);
            else
                pff[i] = *(const float4*)((const float*)Ain + (size_t)t * 64 * K + g * 4);
        }
    }
    __syncthreads();   // bn/Bs/pad ready

    int buf = 0;
    for (; t < NTILES; t += GB) {
        // ---- commit prefetched A into As[buf] (BN fold here)
#pragma unroll
        for (int i = 0; i < NLD; ++i) {
            int g = tid + 256 * i;
            if (g < TOT) {
                int row = g / UPR, u = g - row * UPR;
                if constexpr (ABF16) {
                    uint4 w = pfb[i];
                    if (BNSRC != 0) {
                        unsigned* wp = (unsigned*)&w;
#pragma unroll
                        for (int pp = 0; pp < 4; ++pp) {
                            int kk = u * 8 + 2 * pp;
                            float lo = bf2f((unsigned short)(wp[pp] & 0xFFFFu)) * bnA[kk] + bnB[kk];
                            float hi = bf2f((unsigned short)(wp[pp] >> 16)) * bnA[kk + 1] + bnB[kk + 1];
                            wp[pp] = (unsigned)f2bf(lo) | ((unsigned)f2bf(hi) << 16);
                        }
                    }
                    *(uint4*)&As[buf][row * KS + u * 8] = w;
                } else {
                    float4 v = pff[i];
                    if (BNSRC != 0) {
                        int kk = u * 4;
                        v.x = v.x * bnA[kk] + bnB[kk];
                        v.y = v.y * bnA[kk + 1] + bnB[kk + 1];
                        v.z = v.z * bnA[kk + 2] + bnB[kk + 2];
                        v.w = v.w * bnA[kk + 3] + bnB[kk + 3];
                    }
                    unsigned lo = (unsigned)f2bf(v.x) | ((unsigned)f2bf(v.y) << 16);
                    unsigned hi = (unsigned)f2bf(v.z) | ((unsigned)f2bf(v.w) << 16);
                    *(uint2*)&As[buf][row * KS + u * 4] = make_uint2(lo, hi);
                }
            }
        }
        // ---- issue loads for the NEXT tile (overlap with this tile's MFMA)
        int t2 = t + GB;
        if (t2 < NTILES) {
#pragma unroll
            for (int i = 0; i < NLD; ++i) {
                int g = tid + 256 * i;
                if (g < TOT) {
                    if constexpr (ABF16)
                        pfb[i] = *(const uint4*)((const unsigned short*)Ain + (size_t)t2 * 64 * K + g * 8);
                    else
                        pff[i] = *(const float4*)((const float*)Ain + (size_t)t2 * 64 * K + g * 4);
                }
            }
        }
        __syncthreads();   // As[buf] ready (single barrier per tile; WAR-safe)

        // ---- MFMA
        f32x4 acc[NCF];
#pragma unroll
        for (int cf = 0; cf < NCF; ++cf) acc[cf] = (f32x4){0.f, 0.f, 0.f, 0.f};
#pragma unroll
        for (int kt = 0; kt < KP / 32; ++kt) {
            const int kb = kt * 32 + qd * 8;
            short8 a = *(const short8*)&As[buf][(wv * 16 + lc) * KS + kb];
#pragma unroll
            for (int cf = 0; cf < NCF; ++cf) {
                short8 b = *(const short8*)&Bs[(cf * 16 + lc) * KS + kb];
                acc[cf] = __builtin_amdgcn_mfma_f32_16x16x32_bf16(a, b, acc[cf], 0, 0, 0);
            }
        }
        // ---- epilogue
#pragma unroll
        for (int cf = 0; cf < NCF; ++cf) {
            const int col = cf * 16 + lc;
            const float bv = bvr[cf];
#pragma unroll
            for (int rr = 0; rr < 4; ++rr) {
                float v = acc[cf][rr] + bv;
                int row = t * 64 + wv * 16 + qd * 4 + rr;
                if (OUTBF) ((unsigned short*)Yout)[(size_t)row * MP + col] = f2bf(v);
                else       ((float*)Yout)[(size_t)row * MP + col] = v;
                if (STATS) { cs[cf] += v; cq[cf] += v * v; }
            }
        }
        buf ^= 1;
    }

    if (STATS) {
        __syncthreads();                  // all compute done; reuse As
        float* red = (float*)As;          // [4][MP] sums + [4][MP] sumsq
        float* redq = red + 4 * MP;
#pragma unroll
        for (int cf = 0; cf < NCF; ++cf) {
            float s = cs[cf], qq = cq[cf];
            s += __shfl_down(s, 32, 64); s += __shfl_down(s, 16, 64);
            qq += __shfl_down(qq, 32, 64); qq += __shfl_down(qq, 16, 64);
            if (lane < 16) {
                red[wv * MP + cf * 16 + lane] = s;
                redq[wv * MP + cf * 16 + lane] = qq;
            }
        }
        __syncthreads();
        if (tid < MOUT) {
            float s = red[tid] + red[MP + tid] + red[2 * MP + tid] + red[3 * MP + tid];
            float qq = redq[tid] + redq[MP + tid] + redq[2 * MP + tid] + redq[3 * MP + tid];
            atomicAdd(&sumO[tid], s);
            atomicAdd(&ssO[tid], qq);
        }
    }
}

// ---------------------------------------------------------------------------
// GMM stencil (bf16 TR in, fp32 C out) + BN2 stats as contention-free
// per-block partials (grid 704x256 => column group constant per thread).
// ---------------------------------------------------------------------------
__global__ __launch_bounds__(256) void gmm_stencil(
    const unsigned short* __restrict__ TR, float* __restrict__ C,
    const float* __restrict__ mu, const float* __restrict__ sigma,
    float* __restrict__ partial)
{
    __shared__ float gs[9][3];
    __shared__ float red[88];
    const int tid = threadIdx.x;
    if (tid < 88) red[tid] = 0.f;
    if (tid < 27) {
        int d = tid / 3, k = tid - (tid / 3) * 3;
        int dx = d / 3 - 1, dy = d % 3 - 1;
        float ex = 0.5f * dx + 0.5f, ey = 0.5f * dy + 0.5f;
        float mx = mu[k * 2], my = mu[k * 2 + 1];
        float sx = sigma[k * 2], sy = sigma[k * 2 + 1];
        gs[d][k] = expf(-0.5f * ((ex - mx) * (ex - mx) / (1e-15f + sx * sx) +
                                 (ey - my) * (ey - my) / (1e-15f + sy * sy)));
    }
    __syncthreads();

    const int base = blockIdx.x * 256 + tid;
    const int og = base % 11;
    const int node0 = base / 11;
    const int c0 = og * 4;

    float4 s4 = make_float4(0, 0, 0, 0), q4 = make_float4(0, 0, 0, 0);

    for (int it = 0; it < 9; ++it) {
        int node = node0 + it * 16384;
        int rem = node % (GRIDW * GRIDW);
        int ix = rem / GRIDW, iy = rem - (rem / GRIDW) * GRIDW;
        float ax = 0, ay = 0, az = 0, aw = 0;
#pragma unroll
        for (int dx = -1; dx <= 1; ++dx) {
            int jx = ix + dx;
            if (jx < 0 || jx >= GRIDW) continue;
#pragma unroll
            for (int dy = -1; dy <= 1; ++dy) {
                int jy = iy + dy;
                if (jy < 0 || jy >= GRIDW) continue;
                int d = (dx + 1) * 3 + (dy + 1);
                const unsigned short* tj = TR + (size_t)(node + dx * GRIDW + dy) * 176 + c0;
                float g0 = gs[d][0], g1 = gs[d][1], g2v = gs[d][2];
                ushort4v t0 = *(const ushort4v*)tj;
                ushort4v t1 = *(const ushort4v*)(tj + 44);
                ushort4v t2 = *(const ushort4v*)(tj + 88);
                ax += g0 * bf2f(t0.x) + g1 * bf2f(t1.x) + g2v * bf2f(t2.x);
                ay += g0 * bf2f(t0.y) + g1 * bf2f(t1.y) + g2v * bf2f(t2.y);
                az += g0 * bf2f(t0.z) + g1 * bf2f(t1.z) + g2v * bf2f(t2.z);
                aw += g0 * bf2f(t0.w) + g1 * bf2f(t1.w) + g2v * bf2f(t2.w);
            }
        }
        int cnt = ((ix > 0) + (ix < GRIDW - 1) + 1) * ((iy > 0) + (iy < GRIDW - 1) + 1);
        float inv = 1.f / (float)cnt;
        const unsigned short* rp = TR + (size_t)node * 176 + 132 + c0;
        ushort4v rv = *(const ushort4v*)rp;
        float4 o;
        o.x = ax * inv + bf2f(rv.x);
        o.y = ay * inv + bf2f(rv.y);
        o.z = az * inv + bf2f(rv.z);
        o.w = aw * inv + bf2f(rv.w);
        *(float4*)&C[(size_t)node * 44 + c0] = o;
        s4.x += o.x; s4.y += o.y; s4.z += o.z; s4.w += o.w;
        q4.x += o.x * o.x; q4.y += o.y * o.y; q4.z += o.z * o.z; q4.w += o.w * o.w;
    }
    atomicAdd(&red[c0 + 0], s4.x); atomicAdd(&red[c0 + 1], s4.y);
    atomicAdd(&red[c0 + 2], s4.z); atomicAdd(&red[c0 + 3], s4.w);
    atomicAdd(&red[44 + c0 + 0], q4.x); atomicAdd(&red[44 + c0 + 1], q4.y);
    atomicAdd(&red[44 + c0 + 2], q4.z); atomicAdd(&red[44 + c0 + 3], q4.w);
    __syncthreads();
    if (tid < 88) partial[(size_t)blockIdx.x * 88 + tid] = red[tid];
}

// Reduce 704 partials -> BN2 scale/shift (64-padded with zeros).
__global__ __launch_bounds__(704) void reduce_bn2(
    const float* __restrict__ partial, const float* __restrict__ gamma,
    const float* __restrict__ beta, float* __restrict__ a2p,
    float* __restrict__ sh2p, float invN)
{
    __shared__ float part[8][88];
    __shared__ float tot[88];
    const int tid = threadIdx.x;
    const int c = tid % 88, rg = tid / 88;
    float s = 0.f;
    for (int r = rg; r < 704; r += 8) s += partial[(size_t)r * 88 + c];
    part[rg][c] = s;
    __syncthreads();
    if (tid < 88) {
        float t = 0.f;
#pragma unroll
        for (int g = 0; g < 8; ++g) t += part[g][tid];
        tot[tid] = t;
    }
    __syncthreads();
    if (tid < 64) {
        float a = 0.f, b = 0.f;
        if (tid < 44) {
            float m = tot[tid] * invN;
            float v = tot[44 + tid] * invN - m * m;
            float sc = gamma[tid] * rsqrtf(v + 1e-5f);
            a = sc; b = beta[tid] - m * sc;
        }
        a2p[tid] = a; sh2p[tid] = b;
    }
}

// ---------------------------------------------------------------------------
extern "C" void kernel_launch(void* const* d_in, const int* in_sizes, int n_in,
                              void* d_out, int out_size, void* d_ws, size_t ws_size,
                              hipStream_t stream) {
    const float* x      = (const float*)d_in[0];
    const float* w0     = (const float*)d_in[3];
    const float* b0     = (const float*)d_in[4];
    const float* gamma0 = (const float*)d_in[5];
    const float* beta0  = (const float*)d_in[6];
    const float* w1     = (const float*)d_in[7];
    const float* b1     = (const float*)d_in[8];
    const float* gamma1 = (const float*)d_in[9];
    const float* beta1  = (const float*)d_in[10];
    const float* w2     = (const float*)d_in[11];
    const float* g2     = (const float*)d_in[12];
    const float* mu2    = (const float*)d_in[13];
    const float* sigma2 = (const float*)d_in[14];
    const float* b2     = (const float*)d_in[15];
    const float* gamma2 = (const float*)d_in[16];
    const float* beta2  = (const float*)d_in[17];
    const float* w3     = (const float*)d_in[18];
    const float* b3     = (const float*)d_in[19];
    float* out = (float*)d_out;

    const int N = NNODES;
    const float invN = 1.0f / (float)N;

    // [0,44N): Y1 bf16 (40N f-eq) then C f32 (44N) — disjoint lifetimes
    // [44N,132N): Y0 bf16 (56N f-eq) then TR bf16 (88N f-eq) — disjoint
    const size_t tailOff = (size_t)N * 132;
    size_t need = (tailOff + 84096 + 64) * sizeof(float);
    if (ws_size < need) return;

    float* ws = (float*)d_ws;
    unsigned short* bufY1 = (unsigned short*)ws;
    float*          bufC  = ws;
    unsigned short* bufY0 = (unsigned short*)(ws + (size_t)N * 44);
    unsigned short* bufTR = bufY0;

    float* tail = ws + tailOff;
    float* sum0 = tail;            // 112
    float* ss0  = tail + 112;      // 112
    float* sum1 = tail + 224;      // 80
    float* ss1  = tail + 304;      // 80
    float* a2p  = tail + 384;      // 64
    float* sh2p = tail + 448;      // 64
    float* biasf0 = tail + 512;    // 112
    float* biasf1 = tail + 624;    // 80
    float* biasf2 = tail + 704;    // 176
    float* biasf3 = tail + 880;    // 16
    float* partial = tail + 896;   // 704*88
    unsigned short* wt0 = (unsigned short*)(tail + 62848);  // 112*128
    unsigned short* wt1 = wt0 + 14336;                      // 80*128
    unsigned short* wt2 = wt1 + 10240;                      // 176*96
    unsigned short* wt3 = wt2 + 16896;                      // 16*64

    prep<<<169, 256, 0, stream>>>(w0, b0, w1, b1, g2, w2, b2, w3, b3,
                                  wt0, wt1, wt2, wt3,
                                  biasf0, biasf1, biasf2, biasf3, tail);

    // L0: Y0 = x @ w0 + b0 (bf16 out, stats fused)
    gemm_p<128, 128, 112, 102, 0, 0, true, true, false><<<GB, 256, 0, stream>>>(
        x, wt0, biasf0, nullptr, nullptr, nullptr, nullptr, invN, bufY0, sum0, ss0);

    // L1: Y1 = BN0(Y0) @ w1 + b1 (BN on A-side; stats fused)
    gemm_p<112, 128, 80, 73, 102, 1, true, true, true><<<GB, 256, 0, stream>>>(
        bufY0, wt1, biasf1, sum0, ss0, gamma0, beta0, invN, bufY1, sum1, ss1);

    // L2: TR = BN1(Y1) @ [g2 | w2] (+[0|b2])
    gemm_p<80, 96, 176, 176, 73, 1, false, true, true><<<GB, 256, 0, stream>>>(
        bufY1, wt2, biasf2, sum1, ss1, gamma1, beta1, invN, bufTR, nullptr, nullptr);

    // stencil: C = r + agg(t)/deg ; BN2 stat partials fused
    gmm_stencil<<<704, 256, 0, stream>>>(bufTR, bufC, mu2, sigma2, partial);
    reduce_bn2<<<1, 704, 0, stream>>>(partial, gamma2, beta2, a2p, sh2p, invN);

    // L3: out = BN2(C) @ w3 + b3 (fp32 out)
    gemm_p<44, 64, 16, 16, 64, 2, false, false, false><<<GB, 256, 0, stream>>>(
        bufC, wt3, biasf3, a2p, sh2p, nullptr, nullptr, invN, out, nullptr, nullptr);
}

// Round 8
// 267.016 us; speedup vs baseline: 4.9130x; 1.0806x over previous
//
#include <hip/hip_runtime.h>

#define GRIDW 48
#define NNODES 147456
#define NTILES 2304   // NNODES/64
#define GB 512        // persistent GEMM grid

typedef __attribute__((ext_vector_type(8))) short short8;
typedef __attribute__((ext_vector_type(4))) float f32x4;
typedef __attribute__((ext_vector_type(4))) unsigned short ushort4v;

__device__ inline unsigned short f2bf(float f) {
    union { float f; unsigned u; } v; v.f = f;
    unsigned r = v.u + 0x7FFFu + ((v.u >> 16) & 1u);
    return (unsigned short)(r >> 16);
}
__device__ inline float bf2f(unsigned short h) {
    union { unsigned u; float f; } v; v.u = ((unsigned)h) << 16;
    return v.f;
}

// ---------------------------------------------------------------------------
// prep: weights->bf16 [col][KP] (k-contig, zero-padded), padded biases,
// zero stats (512 floats). One kernel.
// ---------------------------------------------------------------------------
__global__ void prep(const float* __restrict__ w0, const float* __restrict__ b0,
                     const float* __restrict__ w1, const float* __restrict__ b1,
                     const float* __restrict__ g2, const float* __restrict__ w2,
                     const float* __restrict__ b2, const float* __restrict__ w3,
                     const float* __restrict__ b3,
                     unsigned short* __restrict__ wt0, unsigned short* __restrict__ wt1,
                     unsigned short* __restrict__ wt2, unsigned short* __restrict__ wt3,
                     float* __restrict__ biasf0, float* __restrict__ biasf1,
                     float* __restrict__ biasf2, float* __restrict__ biasf3,
                     float* __restrict__ statz) {
    int id = blockIdx.x * 256 + threadIdx.x;
    if (id < 14336) {                         // wt0: 112 cols x 128 k
        int col = id >> 7, k = id & 127;
        wt0[id] = (col < 102) ? f2bf(w0[k * 102 + col]) : (unsigned short)0;
    } else if (id < 24576) {                  // wt1: 80 x 128
        int e = id - 14336; int col = e >> 7, k = e & 127;
        wt1[e] = (col < 73 && k < 102) ? f2bf(w1[k * 73 + col]) : (unsigned short)0;
    } else if (id < 41472) {                  // wt2: 176 x 96 (g2 | w2)
        int e = id - 24576; int col = e / 96, k = e - (e / 96) * 96;
        unsigned short v = 0;
        if (k < 73) v = (col < 132) ? f2bf(g2[k * 132 + col]) : f2bf(w2[k * 44 + (col - 132)]);
        wt2[e] = v;
    } else if (id < 42496) {                  // wt3: 16 x 64
        int e = id - 41472; int col = e >> 6, k = e & 63;
        wt3[e] = (k < 44) ? f2bf(w3[k * 16 + col]) : (unsigned short)0;
    } else if (id < 42608) { int c = id - 42496; biasf0[c] = (c < 102) ? b0[c] : 0.f; }
    else if (id < 42688) { int c = id - 42608; biasf1[c] = (c < 73) ? b1[c] : 0.f; }
    else if (id < 42864) { int c = id - 42688; biasf2[c] = (c < 132) ? 0.f : b2[c - 132]; }
    else if (id < 42880) { int c = id - 42864; biasf3[c] = b3[c]; }
    else if (id < 43392) { statz[id - 42880] = 0.f; }
}

// ---------------------------------------------------------------------------
// Persistent MFMA GEMM, whole-K in LDS, 64-row tiles grid-strided,
// double-buffered A with register prefetch. BN of the previous layer applied
// on the A side during LDS commit.
//   BNSRC 0: none; 1: from (sum,ss,gamma,beta); 2: precomputed (a,b).
// ---------------------------------------------------------------------------
template<int K, int KP, int MP, int MOUT, int PREVM, int BNSRC,
         bool STATS, bool OUTBF, bool ABF16>
__global__ __launch_bounds__(256) void gemm_p(
    const void* __restrict__ Ain, const unsigned short* __restrict__ WT,
    const float* __restrict__ biasf,
    const float* __restrict__ q0, const float* __restrict__ q1,
    const float* __restrict__ q2, const float* __restrict__ q3,
    float invN, void* __restrict__ Yout,
    float* __restrict__ sumO, float* __restrict__ ssO)
{
    constexpr int KS = KP + 8;
    constexpr int NCF = MP / 16;
    constexpr int UPR = ABF16 ? (K / 8) : (K / 4);   // 16B units per row
    constexpr int TOT = 64 * UPR;
    constexpr int NLD = (TOT + 255) / 256;
    __shared__ __align__(16) unsigned short As[2][64 * KS];
    __shared__ __align__(16) unsigned short Bs[MP * KS];
    __shared__ float bnA[KP], bnB[KP];

    const int tid = threadIdx.x;
    const int lane = tid & 63, wv = tid >> 6, qd = lane >> 4, lc = lane & 15;

    if (BNSRC == 1) {
        if (tid < KP) {
            float a = 0.f, b = 0.f;
            if (tid < PREVM) {
                float m = q0[tid] * invN;
                float v = q1[tid] * invN - m * m;
                float sc = q2[tid] * rsqrtf(v + 1e-5f);
                a = sc; b = q3[tid] - m * sc;
            }
            bnA[tid] = a; bnB[tid] = b;
        }
    } else if (BNSRC == 2) {
        if (tid < KP) {
            bnA[tid] = (tid < PREVM) ? q0[tid] : 0.f;
            bnB[tid] = (tid < PREVM) ? q1[tid] : 0.f;
        }
    }
    for (int g = tid; g < MP * (KP / 8); g += 256) {
        int col = g / (KP / 8), u = g - col * (KP / 8);
        *(uint4*)&Bs[col * KS + u * 8] = *(const uint4*)&WT[(size_t)col * KP + u * 8];
    }
    if constexpr (KP > K) {
        constexpr int PADU = (KP - K) / 2;
        for (int g = tid; g < 64 * PADU; g += 256) {
            int row = g / PADU, u = g - row * PADU;
            *(unsigned*)&As[0][row * KS + K + u * 2] = 0u;
            *(unsigned*)&As[1][row * KS + K + u * 2] = 0u;
        }
    }

    float bvr[NCF];
#pragma unroll
    for (int cf = 0; cf < NCF; ++cf) bvr[cf] = biasf[cf * 16 + lc];

    float cs[NCF], cq[NCF];
    if (STATS) {
#pragma unroll
        for (int cf = 0; cf < NCF; ++cf) { cs[cf] = 0.f; cq[cf] = 0.f; }
    }

    uint4 pfb[NLD];
    float4 pff[NLD];

    int t = blockIdx.x;
#pragma unroll
    for (int i = 0; i < NLD; ++i) {
        int g = tid + 256 * i;
        if (g < TOT) {
            if constexpr (ABF16)
                pfb[i] = *(const uint4*)((const unsigned short*)Ain + (size_t)t * 64 * K + g * 8);
            else
                pff[i] = *(const float4*)((const float*)Ain + (size_t)t * 64 * K + g * 4);
        }
    }
    __syncthreads();

    int buf = 0;
    for (; t < NTILES; t += GB) {
#pragma unroll
        for (int i = 0; i < NLD; ++i) {
            int g = tid + 256 * i;
            if (g < TOT) {
                int row = g / UPR, u = g - row * UPR;
                if constexpr (ABF16) {
                    uint4 w = pfb[i];
                    if (BNSRC != 0) {
                        unsigned* wp = (unsigned*)&w;
#pragma unroll
                        for (int pp = 0; pp < 4; ++pp) {
                            int kk = u * 8 + 2 * pp;
                            float lo = bf2f((unsigned short)(wp[pp] & 0xFFFFu)) * bnA[kk] + bnB[kk];
                            float hi = bf2f((unsigned short)(wp[pp] >> 16)) * bnA[kk + 1] + bnB[kk + 1];
                            wp[pp] = (unsigned)f2bf(lo) | ((unsigned)f2bf(hi) << 16);
                        }
                    }
                    *(uint4*)&As[buf][row * KS + u * 8] = w;
                } else {
                    float4 v = pff[i];
                    if (BNSRC != 0) {
                        int kk = u * 4;
                        v.x = v.x * bnA[kk] + bnB[kk];
                        v.y = v.y * bnA[kk + 1] + bnB[kk + 1];
                        v.z = v.z * bnA[kk + 2] + bnB[kk + 2];
                        v.w = v.w * bnA[kk + 3] + bnB[kk + 3];
                    }
                    unsigned lo = (unsigned)f2bf(v.x) | ((unsigned)f2bf(v.y) << 16);
                    unsigned hi = (unsigned)f2bf(v.z) | ((unsigned)f2bf(v.w) << 16);
                    *(uint2*)&As[buf][row * KS + u * 4] = make_uint2(lo, hi);
                }
            }
        }
        int t2 = t + GB;
        if (t2 < NTILES) {
#pragma unroll
            for (int i = 0; i < NLD; ++i) {
                int g = tid + 256 * i;
                if (g < TOT) {
                    if constexpr (ABF16)
                        pfb[i] = *(const uint4*)((const unsigned short*)Ain + (size_t)t2 * 64 * K + g * 8);
                    else
                        pff[i] = *(const float4*)((const float*)Ain + (size_t)t2 * 64 * K + g * 4);
                }
            }
        }
        __syncthreads();

        f32x4 acc[NCF];
#pragma unroll
        for (int cf = 0; cf < NCF; ++cf) acc[cf] = (f32x4){0.f, 0.f, 0.f, 0.f};
#pragma unroll
        for (int kt = 0; kt < KP / 32; ++kt) {
            const int kb = kt * 32 + qd * 8;
            short8 a = *(const short8*)&As[buf][(wv * 16 + lc) * KS + kb];
#pragma unroll
            for (int cf = 0; cf < NCF; ++cf) {
                short8 b = *(const short8*)&Bs[(cf * 16 + lc) * KS + kb];
                acc[cf] = __builtin_amdgcn_mfma_f32_16x16x32_bf16(a, b, acc[cf], 0, 0, 0);
            }
        }
#pragma unroll
        for (int cf = 0; cf < NCF; ++cf) {
            const int col = cf * 16 + lc;
            const float bv = bvr[cf];
#pragma unroll
            for (int rr = 0; rr < 4; ++rr) {
                float v = acc[cf][rr] + bv;
                int row = t * 64 + wv * 16 + qd * 4 + rr;
                if (OUTBF) ((unsigned short*)Yout)[(size_t)row * MP + col] = f2bf(v);
                else       ((float*)Yout)[(size_t)row * MP + col] = v;
                if (STATS) { cs[cf] += v; cq[cf] += v * v; }
            }
        }
        buf ^= 1;
    }

    if (STATS) {
        __syncthreads();
        float* red = (float*)As;
        float* redq = red + 4 * MP;
#pragma unroll
        for (int cf = 0; cf < NCF; ++cf) {
            float s = cs[cf], qq = cq[cf];
            s += __shfl_down(s, 32, 64); s += __shfl_down(s, 16, 64);
            qq += __shfl_down(qq, 32, 64); qq += __shfl_down(qq, 16, 64);
            if (lane < 16) {
                red[wv * MP + cf * 16 + lane] = s;
                redq[wv * MP + cf * 16 + lane] = qq;
            }
        }
        __syncthreads();
        if (tid < MOUT) {
            float s = red[tid] + red[MP + tid] + red[2 * MP + tid] + red[3 * MP + tid];
            float qq = redq[tid] + redq[MP + tid] + redq[2 * MP + tid] + redq[3 * MP + tid];
            atomicAdd(&sumO[tid], s);
            atomicAdd(&ssO[tid], qq);
        }
    }
}

// ---------------------------------------------------------------------------
// GMM stencil, band-tiled: block = (batch, 6-row band); 288 nodes/block.
// XCD swizzle keeps all 8 bands of a batch on one XCD (TR batch = 405 KB,
// 8 batches ~ 3.2 MB < 4 MB L2) so halo rows re-hit local L2.
// Threads t<253: og = t%11 constant -> register stats; C stored bf16 N x 48
// (cols 44..47 zero); block partials atomically added to sum2/ss2.
// ---------------------------------------------------------------------------
__global__ __launch_bounds__(256) void gmm_stencil(
    const unsigned short* __restrict__ TR, unsigned short* __restrict__ C,
    const float* __restrict__ mu, const float* __restrict__ sigma,
    float* __restrict__ sum2, float* __restrict__ ss2)
{
    __shared__ float gs[9][3];
    __shared__ float red[88];
    const int tid = threadIdx.x;
    if (tid < 88) red[tid] = 0.f;
    if (tid < 27) {
        int d = tid / 3, k = tid - (tid / 3) * 3;
        int dx = d / 3 - 1, dy = d % 3 - 1;
        float ex = 0.5f * dx + 0.5f, ey = 0.5f * dy + 0.5f;
        float mx = mu[k * 2], my = mu[k * 2 + 1];
        float sx = sigma[k * 2], sy = sigma[k * 2 + 1];
        gs[d][k] = expf(-0.5f * ((ex - mx) * (ex - mx) / (1e-15f + sx * sx) +
                                 (ey - my) * (ey - my) / (1e-15f + sy * sy)));
    }
    __syncthreads();

    // XCD-aware block -> (batch, band): blocks with equal blk%8 (same XCD
    // under round-robin) cover all bands of 8 consecutive batches.
    const int r = blockIdx.x & 7;
    const int m = blockIdx.x >> 3;
    const int batch = r * 8 + (m >> 3);
    const int band = m & 7;
    const int base = batch * 2304 + band * 288;

    if (tid < 253) {
        const int og = tid % 11;
        const int ln0 = tid / 11;
        const int c0 = og * 4;
        float4 s4 = make_float4(0, 0, 0, 0), q4 = make_float4(0, 0, 0, 0);

        for (int i = 0; i < 13; ++i) {
            int ln = ln0 + 23 * i;
            if (ln >= 288) break;
            int node = base + ln;
            int rx = ln / 48, iy = ln - rx * 48;
            int ix = band * 6 + rx;
            float ax = 0, ay = 0, az = 0, aw = 0;
#pragma unroll
            for (int dx = -1; dx <= 1; ++dx) {
                int jx = ix + dx;
                if (jx < 0 || jx >= GRIDW) continue;
#pragma unroll
                for (int dy = -1; dy <= 1; ++dy) {
                    int jy = iy + dy;
                    if (jy < 0 || jy >= GRIDW) continue;
                    int d = (dx + 1) * 3 + (dy + 1);
                    const unsigned short* tj = TR + (size_t)(node + dx * GRIDW + dy) * 176 + c0;
                    float g0 = gs[d][0], g1 = gs[d][1], g2v = gs[d][2];
                    ushort4v t0 = *(const ushort4v*)tj;
                    ushort4v t1 = *(const ushort4v*)(tj + 44);
                    ushort4v t2 = *(const ushort4v*)(tj + 88);
                    ax += g0 * bf2f(t0.x) + g1 * bf2f(t1.x) + g2v * bf2f(t2.x);
                    ay += g0 * bf2f(t0.y) + g1 * bf2f(t1.y) + g2v * bf2f(t2.y);
                    az += g0 * bf2f(t0.z) + g1 * bf2f(t1.z) + g2v * bf2f(t2.z);
                    aw += g0 * bf2f(t0.w) + g1 * bf2f(t1.w) + g2v * bf2f(t2.w);
                }
            }
            int cnt = ((ix > 0) + (ix < GRIDW - 1) + 1) * ((iy > 0) + (iy < GRIDW - 1) + 1);
            float inv = 1.f / (float)cnt;
            const unsigned short* rp = TR + (size_t)node * 176 + 132 + c0;
            ushort4v rv = *(const ushort4v*)rp;
            float ox = ax * inv + bf2f(rv.x);
            float oy = ay * inv + bf2f(rv.y);
            float oz = az * inv + bf2f(rv.z);
            float ow = aw * inv + bf2f(rv.w);
            unsigned lo = (unsigned)f2bf(ox) | ((unsigned)f2bf(oy) << 16);
            unsigned hi = (unsigned)f2bf(oz) | ((unsigned)f2bf(ow) << 16);
            *(uint2*)&C[(size_t)node * 48 + c0] = make_uint2(lo, hi);
            if (og == 10)   // zero the pad cols 44..47
                *(uint2*)&C[(size_t)node * 48 + 44] = make_uint2(0u, 0u);
            s4.x += ox; s4.y += oy; s4.z += oz; s4.w += ow;
            q4.x += ox * ox; q4.y += oy * oy; q4.z += oz * oz; q4.w += ow * ow;
        }
        atomicAdd(&red[c0 + 0], s4.x); atomicAdd(&red[c0 + 1], s4.y);
        atomicAdd(&red[c0 + 2], s4.z); atomicAdd(&red[c0 + 3], s4.w);
        atomicAdd(&red[44 + c0 + 0], q4.x); atomicAdd(&red[44 + c0 + 1], q4.y);
        atomicAdd(&red[44 + c0 + 2], q4.z); atomicAdd(&red[44 + c0 + 3], q4.w);
    }
    __syncthreads();
    if (tid < 44) atomicAdd(&sum2[tid], red[tid]);
    else if (tid < 88) atomicAdd(&ss2[tid - 44], red[tid]);
}

// ---------------------------------------------------------------------------
extern "C" void kernel_launch(void* const* d_in, const int* in_sizes, int n_in,
                              void* d_out, int out_size, void* d_ws, size_t ws_size,
                              hipStream_t stream) {
    const float* x      = (const float*)d_in[0];
    const float* w0     = (const float*)d_in[3];
    const float* b0     = (const float*)d_in[4];
    const float* gamma0 = (const float*)d_in[5];
    const float* beta0  = (const float*)d_in[6];
    const float* w1     = (const float*)d_in[7];
    const float* b1     = (const float*)d_in[8];
    const float* gamma1 = (const float*)d_in[9];
    const float* beta1  = (const float*)d_in[10];
    const float* w2     = (const float*)d_in[11];
    const float* g2     = (const float*)d_in[12];
    const float* mu2    = (const float*)d_in[13];
    const float* sigma2 = (const float*)d_in[14];
    const float* b2     = (const float*)d_in[15];
    const float* gamma2 = (const float*)d_in[16];
    const float* beta2  = (const float*)d_in[17];
    const float* w3     = (const float*)d_in[18];
    const float* b3     = (const float*)d_in[19];
    float* out = (float*)d_out;

    const int N = NNODES;
    const float invN = 1.0f / (float)N;

    // [0,44N): Y1 bf16 (40N f-eq) then C bf16 48 cols (24N f-eq) — disjoint
    // [44N,132N): Y0 bf16 (56N f-eq) then TR bf16 (88N f-eq) — disjoint
    const size_t tailOff = (size_t)N * 132;
    size_t need = (tailOff + 90000) * sizeof(float);
    if (ws_size < need) return;

    float* ws = (float*)d_ws;
    unsigned short* bufY1 = (unsigned short*)ws;
    unsigned short* bufC  = (unsigned short*)ws;
    unsigned short* bufY0 = (unsigned short*)(ws + (size_t)N * 44);
    unsigned short* bufTR = bufY0;

    float* tail = ws + tailOff;
    float* sum0 = tail;            // 112
    float* ss0  = tail + 112;      // 112
    float* sum1 = tail + 224;      // 80
    float* ss1  = tail + 304;      // 80
    float* sum2 = tail + 384;      // 44
    float* ss2  = tail + 448;      // 44
    float* biasf0 = tail + 512;    // 112
    float* biasf1 = tail + 624;    // 80
    float* biasf2 = tail + 704;    // 176
    float* biasf3 = tail + 880;    // 16
    unsigned short* wt0 = (unsigned short*)(tail + 896);    // 112*128
    unsigned short* wt1 = wt0 + 14336;                      // 80*128
    unsigned short* wt2 = wt1 + 10240;                      // 176*96
    unsigned short* wt3 = wt2 + 16896;                      // 16*64

    prep<<<169, 256, 0, stream>>>(w0, b0, w1, b1, g2, w2, b2, w3, b3,
                                  wt0, wt1, wt2, wt3,
                                  biasf0, biasf1, biasf2, biasf3, tail);

    // L0: Y0 = x @ w0 + b0 (bf16 out, stats fused)
    gemm_p<128, 128, 112, 102, 0, 0, true, true, false><<<GB, 256, 0, stream>>>(
        x, wt0, biasf0, nullptr, nullptr, nullptr, nullptr, invN, bufY0, sum0, ss0);

    // L1: Y1 = BN0(Y0) @ w1 + b1 (BN on A-side; stats fused)
    gemm_p<112, 128, 80, 73, 102, 1, true, true, true><<<GB, 256, 0, stream>>>(
        bufY0, wt1, biasf1, sum0, ss0, gamma0, beta0, invN, bufY1, sum1, ss1);

    // L2: TR = BN1(Y1) @ [g2 | w2] (+[0|b2])
    gemm_p<80, 96, 176, 176, 73, 1, false, true, true><<<GB, 256, 0, stream>>>(
        bufY1, wt2, biasf2, sum1, ss1, gamma1, beta1, invN, bufTR, nullptr, nullptr);

    // stencil: C(bf16,48) = r + agg(t)/deg ; BN2 stats direct to sum2/ss2
    gmm_stencil<<<512, 256, 0, stream>>>(bufTR, bufC, mu2, sigma2, sum2, ss2);

    // L3: out = BN2(C) @ w3 + b3 (fp32 out; BN fold from sums)
    gemm_p<48, 64, 16, 16, 44, 1, false, false, true><<<GB, 256, 0, stream>>>(
        bufC, wt3, biasf3, sum2, ss2, gamma2, beta2, invN, out, nullptr, nullptr);
}